// Round 4
// baseline (230.112 us; speedup 1.0000x reference)
//
#include <hip/hip_runtime.h>
#include <hip/hip_bf16.h>
#include <stdint.h>
#include <stddef.h>

typedef unsigned short u16;
typedef __bf16 bf16x8 __attribute__((ext_vector_type(8)));
typedef __bf16 bf16x2 __attribute__((ext_vector_type(2)));
typedef float f32x4 __attribute__((ext_vector_type(4)));
typedef unsigned short u16x8 __attribute__((ext_vector_type(8)));
typedef unsigned short u16x4 __attribute__((ext_vector_type(4)));

#define NBATCH 4
#define LSEQ   2048
#define CDIM   512
#define NHEADS 8
#define DHEAD  64
// q pre-scale folds softmax exp->exp2: 0.125 * log2(e)
#define QSCALE 0.18033688011112042f

// native v_exp_f32 (computes 2^x); __exp2f fails to compile in this harness
__device__ __forceinline__ float exp2_hw(float x) {
  return __builtin_amdgcn_exp2f(x);
}

__device__ __forceinline__ u16 f2bf(float f) {
  union { float f; unsigned u; } v; v.f = f;
  return (u16)((v.u + 0x7FFFu + ((v.u >> 16) & 1u)) >> 16);  // RNE
}
__device__ __forceinline__ u16 f2bf_hw(float f) {
  union { __bf16 b; u16 u; } cv; cv.b = (__bf16)f; return cv.u;
}
__device__ __forceinline__ unsigned pack2bf(float a, float b) {
  union { bf16x2 v; unsigned u; } cv;
  cv.v[0] = (__bf16)a; cv.v[1] = (__bf16)b;
  return cv.u;
}
__device__ __forceinline__ f32x4 mfma16(bf16x8 a, bf16x8 b, f32x4 c) {
  return __builtin_amdgcn_mfma_f32_16x16x32_bf16(a, b, c, 0, 0, 0);
}
// async global->LDS, 16B/lane. lp wave-uniform; HW writes lp + lane*16.
__device__ __forceinline__ void async16(const u16* gp, const u16* lp) {
  auto* g = reinterpret_cast<const __attribute__((address_space(1))) uint32_t*>(
      reinterpret_cast<uintptr_t>(gp));
  auto* l = reinterpret_cast<__attribute__((address_space(3))) uint32_t*>(
      reinterpret_cast<uintptr_t>(lp));
  __builtin_amdgcn_global_load_lds(g, l, 16, 0, 0);
}

// ---------------------------------------------------------------------------
// Kernel 1 (merged): blocks [0,4096) transpose x -> xT bf16; [4096,5120)
// convert w_qkv/w_out -> bf16.
__global__ __launch_bounds__(256) void prep(const float* __restrict__ x,
                                            const float* __restrict__ wqkv,
                                            const float* __restrict__ wout,
                                            u16* __restrict__ xT,
                                            u16* __restrict__ wqkvb,
                                            u16* __restrict__ woutb) {
  __shared__ u16 tile[32][36];
  int b = blockIdx.x, t = threadIdx.x;
  if (b < 4096) {
    int lb = b & 63, cb = (b >> 6) & 15, n = b >> 10;
    int c = t >> 3, lq = (t & 7) * 4;
    float4 f = *(const float4*)(x + ((size_t)(n * CDIM + cb * 32 + c)) * LSEQ + lb * 32 + lq);
    u16x4 cv;
    cv[0] = f2bf(f.x); cv[1] = f2bf(f.y); cv[2] = f2bf(f.z); cv[3] = f2bf(f.w);
    *(u16x4*)&tile[c][lq] = cv;
    __syncthreads();
    int l = t >> 3, cq = (t & 7) * 4;
    u16x4 o;
    o[0] = tile[cq + 0][l]; o[1] = tile[cq + 1][l];
    o[2] = tile[cq + 2][l]; o[3] = tile[cq + 3][l];
    *(u16x4*)(xT + ((size_t)(n * LSEQ + lb * 32 + l)) * CDIM + cb * 32 + cq) = o;
  } else {
    int i = (b - 4096) * 256 + t;  // 1024 blocks * 256 = 262144 float4s
    const float4* src;
    u16* dst;
    int idx;
    if (i < 196608) { src = (const float4*)wqkv; dst = wqkvb; idx = i; }
    else            { src = (const float4*)wout; dst = woutb; idx = i - 196608; }
    float4 f = src[idx];
    u16x4 o;
    o[0] = f2bf(f.x); o[1] = f2bf(f.y); o[2] = f2bf(f.z); o[3] = f2bf(f.w);
    *(u16x4*)(dst + (size_t)idx * 4) = o;
  }
}

// ---------------------------------------------------------------------------
// Kernel 2 (m97-style): QKV GEMM, 128x128 tile, BK=64. grid: (12, 16, 4).
__global__ __launch_bounds__(256, 3) void qkv_gemm(const u16* __restrict__ wqkvb,
                                                   const u16* __restrict__ xT,
                                                   u16* __restrict__ qT,
                                                   u16* __restrict__ kT,
                                                   u16* __restrict__ vp) {
  __shared__ __align__(16) u16 lds[17408];  // main: At|Bt 2x8192; epi: 128x136
  u16* At = lds;
  u16* Bt = lds + 8192;

  int mb = blockIdx.x, lb = blockIdx.y, n = blockIdx.z;
  int o0 = mb * 128, l0 = lb * 128;
  int t = threadIdx.x, w = t >> 6, lane = t & 63, quad = lane >> 4, l15 = lane & 15;
  int wr = w >> 1, wc = w & 1;
  int lr = lane >> 3, lc = lane & 7;
  int swzS = (lc ^ lr) * 8;
  int swzR = l15 & 7;

  const u16* ag = wqkvb + (size_t)(o0 + w * 32 + lr) * CDIM + swzS;
  const u16* bg = xT + ((size_t)n * LSEQ + l0 + w * 32 + lr) * CDIM + swzS;

  f32x4 acc[4][4];
#pragma unroll
  for (int i = 0; i < 4; ++i)
#pragma unroll
    for (int j = 0; j < 4; ++j) acc[i][j] = (f32x4)0.0f;

  for (int k0 = 0; k0 < CDIM; k0 += 64) {
#pragma unroll
    for (int g = 0; g < 4; ++g) {
      async16(ag + (size_t)g * 8 * CDIM + k0, At + (w * 32 + g * 8) * 64);
      async16(bg + (size_t)g * 8 * CDIM + k0, Bt + (w * 32 + g * 8) * 64);
    }
    __syncthreads();
    bf16x8 af[4][2], bf[4][2];
#pragma unroll
    for (int rt = 0; rt < 4; ++rt)
#pragma unroll
      for (int kk = 0; kk < 2; ++kk) {
        af[rt][kk] = *(const bf16x8*)&At[(wr * 64 + rt * 16 + l15) * 64 +
                                         (((kk * 4 + quad) ^ swzR) * 8)];
        bf[rt][kk] = *(const bf16x8*)&Bt[(wc * 64 + rt * 16 + l15) * 64 +
                                         (((kk * 4 + quad) ^ swzR) * 8)];
      }
#pragma unroll
    for (int kk = 0; kk < 2; ++kk)
#pragma unroll
      for (int rt = 0; rt < 4; ++rt)
#pragma unroll
        for (int ct = 0; ct < 4; ++ct)
          acc[rt][ct] = mfma16(af[rt][kk], bf[ct][kk], acc[rt][ct]);
    __syncthreads();
  }

  int seg = mb >> 2;        // 0 q, 1 k, 2 v
  int hb = (mb & 3) * 2;    // 2 heads per block
  if (seg < 2) {
    float scale = (seg == 0) ? QSCALE : 1.0f;
#pragma unroll
    for (int rt = 0; rt < 4; ++rt)
#pragma unroll
      for (int ct = 0; ct < 4; ++ct) {
        u16x4 ov;
#pragma unroll
        for (int r = 0; r < 4; ++r) ov[r] = f2bf_hw(acc[rt][ct][r] * scale);
        *(u16x4*)&lds[(wc * 64 + ct * 16 + l15) * 136 + wr * 64 + rt * 16 + quad * 4] = ov;
      }
    __syncthreads();
    u16* dst0 = (seg == 0) ? qT : kT;
#pragma unroll
    for (int p = 0; p < 8; ++p) {
      int l = p * 16 + (t >> 4);
      int ch = t & 15;
      u16x8 val = *(const u16x8*)&lds[l * 136 + ch * 8];
      int h = hb + (ch >> 3);
      int d = (ch & 7) * 8;
      *(u16x8*)(dst0 + (((size_t)(n * NHEADS + h)) * LSEQ + l0 + l) * DHEAD + d) = val;
    }
  } else {
#pragma unroll
    for (int rt = 0; rt < 4; ++rt)
#pragma unroll
      for (int ct = 0; ct < 4; ++ct)
#pragma unroll
        for (int r = 0; r < 4; ++r)
          lds[(wr * 64 + rt * 16 + quad * 4 + r) * 136 + wc * 64 + ct * 16 + l15] =
              f2bf_hw(acc[rt][ct][r]);
    __syncthreads();
#pragma unroll
    for (int p = 0; p < 8; ++p) {
      int o = p * 16 + (t >> 4);
      int ch = t & 15;
      u16x8 val = *(const u16x8*)&lds[o * 136 + ch * 8];
      int h = hb + (o >> 6);
      int d = o & 63;
      *(u16x8*)(vp + (((size_t)(n * NHEADS + h)) * DHEAD + d) * LSEQ + l0 + ch * 8) = val;
    }
  }
}

// ---------------------------------------------------------------------------
// Kernel 3: flash attention (constant-shift softmax, no online max).
//
// R3 post-mortem: Pt-removal (in-register permlane transpose) delivered
// -11% and killed bank conflicts, confirming the DS-pipe occupancy model.
// Remaining DS cost: kf/vf ds_read_b128 (1536cy) + staging (256cy) ~54% of
// the 3353cy CU-tile wall — all of it just a global->LDS->reg broadcast.
//
// R-this: K/V fragments loaded DIRECTLY global->VGPR (no LDS, no barriers,
// no async DMA in the main loop). Per (jt,kk) load the wave covers 16
// contiguous 64B segments (quads 0..3 = cols 0..63B of 16 rows) — fully
// coalesced at 64B granularity. Per-tile K+V footprint per block = 16KB,
// fits L1 (32KB): the 4 waves issue identical K/V addresses, so ~3/4 are
// L1 hits; L2 traffic ~256MB/dispatch ~ 7TB/s, well under ceiling.
// 2-deep register pipeline (all names static, rule #20):
//   body(t): PV(t-1) from vf_prev/pf_c; load K/V(t+1) into the buffer PV
//   just freed; QK(t) from kf_cur; softmax -> pf_c. A/B alternate by parity.
// Waves run fully independent; only the output-transpose epilogue uses LDS.
// 4 waves x 32 q-rows = 128 rows/block; grid: (16, 8, 4), block 256.
__global__ __launch_bounds__(256, 2) void attn_kernel(const u16* __restrict__ qT,
                                                      const u16* __restrict__ kT,
                                                      const u16* __restrict__ vp,
                                                      u16* __restrict__ aoT) {
  __shared__ __align__(16) u16 Ot[128 * 72];  // epilogue transpose only (18KB)

  int ib = blockIdx.x, h = blockIdx.y, n = blockIdx.z;
  int i0 = ib * 128;
  const u16* qb = qT + ((size_t)(n * NHEADS + h)) * LSEQ * DHEAD;
  const u16* kb = kT + ((size_t)(n * NHEADS + h)) * LSEQ * DHEAD;
  const u16* vb = vp + ((size_t)(n * NHEADS + h)) * DHEAD * LSEQ;
  int t = threadIdx.x, w = t >> 6, lane = t & 63, quad = lane >> 4, l15 = lane & 15;

  // Q B-frags (resident). qf[it][kk]: Q[i = i0+w*32+it*16+l15][kk*32+quad*8 ..]
  bf16x8 qf[2][2];
#pragma unroll
  for (int it = 0; it < 2; ++it)
#pragma unroll
    for (int kk = 0; kk < 2; ++kk)
      qf[it][kk] = *(const bf16x8*)(qb + (size_t)(i0 + w * 32 + it * 16 + l15) * DHEAD +
                                    kk * 32 + quad * 8);

  f32x4 Oc[2][4];
#pragma unroll
  for (int it = 0; it < 2; ++it)
#pragma unroll
    for (int dt = 0; dt < 4; ++dt) Oc[it][dt] = (f32x4)0.0f;
  float lsum[2] = {0.f, 0.f};  // per-lane partial row sums

  // Per-lane fragment bases (bf16x8 = 16B per lane):
  //   kf[jt][kk] = K[16jt+l15][(4kk+quad)*8 ..]   (K row stride 64 u16)
  //   vf[dt][kk] = V[d=16dt+l15][j0+(4kk+quad)*8] (V row stride LSEQ u16)
  const u16* kbl = kb + l15 * 64 + quad * 8;
  const u16* vbl = vb + (size_t)l15 * LSEQ + quad * 8;

  // Double-buffered K/V register tiles (static names only — rule #20).
  bf16x8 kfA[4][2], vfA[4][2], kfB[4][2], vfB[4][2];
  bf16x8 pf_c[2][2];  // P^T B-frags of the previous tile

  auto load_k = [&](int tt, bf16x8 (&kf)[4][2]) {
#pragma unroll
    for (int jt = 0; jt < 4; ++jt)
#pragma unroll
      for (int kk = 0; kk < 2; ++kk)
        kf[jt][kk] = *(const bf16x8*)(kbl + (size_t)tt * 4096 + jt * 1024 + kk * 32);
  };
  auto load_v = [&](int tt, bf16x8 (&vf)[4][2]) {
#pragma unroll
    for (int dt = 0; dt < 4; ++dt)
#pragma unroll
      for (int kk = 0; kk < 2; ++kk)
        vf[dt][kk] = *(const bf16x8*)(vbl + (size_t)dt * 16 * LSEQ + tt * 64 + kk * 32);
  };

  // QK^T + softmax + in-register P^T transpose (permlane swaps; see R3
  // derivation: (Ah,Bh)=swap16(swap32(w[2kk][h],w[2kk+1][h])) gives u32
  // slots h / 2+h of pf[kk], j = 32kk+8q'+e, i preserved).
  auto qk_soft = [&](bf16x8 (&kf)[4][2]) {
    f32x4 st[2][4];
#pragma unroll
    for (int it = 0; it < 2; ++it)
#pragma unroll
      for (int jt = 0; jt < 4; ++jt) {
        f32x4 s = (f32x4)0.0f;
        s = mfma16(kf[jt][0], qf[it][0], s);
        s = mfma16(kf[jt][1], qf[it][1], s);
        st[it][jt] = s;
      }
#pragma unroll
    for (int it = 0; it < 2; ++it) {
      unsigned wjh[4][2];
#pragma unroll
      for (int jt = 0; jt < 4; ++jt) {
        float p0 = exp2_hw(st[it][jt][0]);
        float p1 = exp2_hw(st[it][jt][1]);
        float p2 = exp2_hw(st[it][jt][2]);
        float p3 = exp2_hw(st[it][jt][3]);
        lsum[it] += (p0 + p1) + (p2 + p3);
        wjh[jt][0] = pack2bf(p0, p1);
        wjh[jt][1] = pack2bf(p2, p3);
      }
#pragma unroll
      for (int kk = 0; kk < 2; ++kk) {
        unsigned a0 = wjh[2 * kk][0], b0 = wjh[2 * kk + 1][0];
        unsigned a1 = wjh[2 * kk][1], b1 = wjh[2 * kk + 1][1];
        asm volatile("v_permlane32_swap_b32 %0, %1" : "+v"(a0), "+v"(b0));
        asm volatile("v_permlane16_swap_b32 %0, %1" : "+v"(a0), "+v"(b0));
        asm volatile("v_permlane32_swap_b32 %0, %1" : "+v"(a1), "+v"(b1));
        asm volatile("v_permlane16_swap_b32 %0, %1" : "+v"(a1), "+v"(b1));
        union { unsigned u[4]; bf16x8 v; } cv;
        cv.u[0] = a0; cv.u[1] = a1; cv.u[2] = b0; cv.u[3] = b1;
        pf_c[it][kk] = cv.v;
      }
    }
  };

  auto pv = [&](bf16x8 (&vf)[4][2]) {
#pragma unroll
    for (int it = 0; it < 2; ++it)
#pragma unroll
      for (int dt = 0; dt < 4; ++dt) {
        Oc[it][dt] = mfma16(vf[dt][0], pf_c[it][0], Oc[it][dt]);
        Oc[it][dt] = mfma16(vf[dt][1], pf_c[it][1], Oc[it][dt]);
      }
  };

  // ---- Prologue: tiles 0,1 in flight; QK(0) ----
  load_k(0, kfA); load_v(0, vfA);
  load_k(1, kfB); load_v(1, vfB);
  qk_soft(kfA);  // pf_c = P(0); vfA = V(0) live

  // ---- Main loop (unrolled x2 for A/B parity): bodies t=1..30 ----
  for (int tb = 1; tb < 31; tb += 2) {
    // body t=tb (odd): cur=B, prev=A
    pv(vfA);                                  // PV(tb-1)
    load_k(tb + 1, kfA); load_v(tb + 1, vfA); // tile tb+1 -> A
    qk_soft(kfB);                             // P(tb)
    // body t=tb+1 (even): cur=A, prev=B
    pv(vfB);                                  // PV(tb)
    load_k(tb + 2, kfB); load_v(tb + 2, vfB); // tile tb+2 -> B
    qk_soft(kfA);                             // P(tb+1)
  }

  // ---- Peeled body t=31 (odd): no further loads ----
  pv(vfA);        // PV(30)
  qk_soft(kfB);   // P(31)
  pv(vfB);        // PV(31) drain

  // Epilogue: single cross-quad reduce of lsum, normalize, transpose via LDS.
#pragma unroll
  for (int it = 0; it < 2; ++it) {
    lsum[it] += __shfl_xor(lsum[it], 16, 64);
    lsum[it] += __shfl_xor(lsum[it], 32, 64);
  }
#pragma unroll
  for (int it = 0; it < 2; ++it) {
    float inv = 1.0f / lsum[it];
#pragma unroll
    for (int dt = 0; dt < 4; ++dt) {
      u16x4 ov;
#pragma unroll
      for (int r = 0; r < 4; ++r) ov[r] = f2bf_hw(Oc[it][dt][r] * inv);
      *(u16x4*)&Ot[(w * 32 + it * 16 + l15) * 72 + 16 * dt + 4 * quad] = ov;
    }
  }
  __syncthreads();
#pragma unroll
  for (int p = 0; p < 4; ++p) {
    int row = p * 32 + (t >> 3);
    u16x8 val = *(const u16x8*)&Ot[row * 72 + (t & 7) * 8];
    *(u16x8*)(aoT + ((size_t)n * LSEQ + i0 + row) * CDIM + h * DHEAD + (t & 7) * 8) = val;
  }
}

// ---------------------------------------------------------------------------
// Kernel 4 (R6 two-barrier single-buffer): out GEMM + bias, 128x128 tile,
// BK=64. grid: (4, 16, 4).
__global__ __launch_bounds__(256, 3) void out_gemm(const u16* __restrict__ woutb,
                                                   const u16* __restrict__ aoT,
                                                   const float* __restrict__ bout,
                                                   float* __restrict__ out) {
  __shared__ __align__(16) u16 lds[16384];  // At|Bt 2x8192
  u16* At = lds;
  u16* Bt = lds + 8192;

  int mb = blockIdx.x, lb = blockIdx.y, n = blockIdx.z;
  int o0 = mb * 128, l0 = lb * 128;
  int t = threadIdx.x, w = t >> 6, lane = t & 63, quad = lane >> 4, l15 = lane & 15;
  int wr = w >> 1, wc = w & 1;
  int lr = lane >> 3, lc = lane & 7;
  int swzS = (lc ^ lr) * 8;
  int swzR = l15 & 7;

  const u16* ag = woutb + (size_t)(o0 + w * 32 + lr) * CDIM + swzS;
  const u16* bg = aoT + ((size_t)n * LSEQ + l0 + w * 32 + lr) * CDIM + swzS;

  f32x4 acc[4][4];
#pragma unroll
  for (int i = 0; i < 4; ++i)
#pragma unroll
    for (int j = 0; j < 4; ++j) acc[i][j] = (f32x4)0.0f;

  for (int k0 = 0; k0 < CDIM; k0 += 64) {
#pragma unroll
    for (int g = 0; g < 4; ++g) {
      async16(ag + (size_t)g * 8 * CDIM + k0, At + (w * 32 + g * 8) * 64);
      async16(bg + (size_t)g * 8 * CDIM + k0, Bt + (w * 32 + g * 8) * 64);
    }
    __syncthreads();
    bf16x8 af[4][2], bf[4][2];
#pragma unroll
    for (int rt = 0; rt < 4; ++rt)
#pragma unroll
      for (int kk = 0; kk < 2; ++kk) {
        af[rt][kk] = *(const bf16x8*)&At[(wr * 64 + rt * 16 + l15) * 64 +
                                         (((kk * 4 + quad) ^ swzR) * 8)];
        bf[rt][kk] = *(const bf16x8*)&Bt[(wc * 64 + rt * 16 + l15) * 64 +
                                         (((kk * 4 + quad) ^ swzR) * 8)];
      }
#pragma unroll
    for (int kk = 0; kk < 2; ++kk)
#pragma unroll
      for (int rt = 0; rt < 4; ++rt)
#pragma unroll
        for (int ct = 0; ct < 4; ++ct)
          acc[rt][ct] = mfma16(af[rt][kk], bf[ct][kk], acc[rt][ct]);
    __syncthreads();
  }

#pragma unroll
  for (int rt = 0; rt < 4; ++rt) {
    int orow = o0 + wr * 64 + rt * 16 + quad * 4;
#pragma unroll
    for (int r = 0; r < 4; ++r) {
      float bb = bout[orow + r];
      float* orow_p = out + ((size_t)n * CDIM + orow + r) * LSEQ + l0 + wc * 64;
#pragma unroll
      for (int ct = 0; ct < 4; ++ct)
        orow_p[ct * 16 + l15] = acc[rt][ct][r] + bb;
    }
  }
}

// ---------------------------------------------------------------------------
extern "C" void kernel_launch(void* const* d_in, const int* in_sizes, int n_in,
                              void* d_out, int out_size, void* d_ws, size_t ws_size,
                              hipStream_t stream) {
  (void)in_sizes; (void)n_in; (void)out_size; (void)ws_size;
  const float* x    = (const float*)d_in[0];  // [4,512,2048]
  const float* wqkv = (const float*)d_in[1];  // [1536,512]
  const float* wout = (const float*)d_in[2];  // [512,512]
  const float* bout = (const float*)d_in[3];  // [512]

  char* ws = (char*)d_ws;
  u16* xT    = (u16*)(ws + 0);           // x^T [n][l][c]
  u16* wqkvb = (u16*)(ws + 8388608);
  u16* woutb = (u16*)(ws + 9961472);
  u16* qT    = (u16*)(ws + 10485760);    // [n][h][l][d], pre-scaled by QSCALE
  u16* kT    = (u16*)(ws + 18874368);    // [n][h][l][d]
  u16* vp    = (u16*)(ws + 27262976);    // [n][h][d][l]
  u16* aoT   = (u16*)(ws + 35651584);    // [n][l][h*64+d]

  hipLaunchKernelGGL(prep, dim3(5120), dim3(256), 0, stream, x, wqkv, wout, xT, wqkvb, woutb);
  hipLaunchKernelGGL(qkv_gemm, dim3(12, 16, 4), dim3(256), 0, stream, wqkvb, xT, qT, kT, vp);
  hipLaunchKernelGGL(attn_kernel, dim3(16, 8, 4), dim3(256), 0, stream, qT, kT, vp, aoT);
  hipLaunchKernelGGL(out_gemm, dim3(4, 16, 4), dim3(256), 0, stream, woutb, aoT, bout,
                     (float*)d_out);
}

// Round 5
// 148.519 us; speedup vs baseline: 1.5494x; 1.5494x over previous
//
#include <hip/hip_runtime.h>
#include <hip/hip_bf16.h>
#include <stdint.h>
#include <stddef.h>

typedef unsigned short u16;
typedef __bf16 bf16x8 __attribute__((ext_vector_type(8)));
typedef __bf16 bf16x2 __attribute__((ext_vector_type(2)));
typedef float f32x4 __attribute__((ext_vector_type(4)));
typedef unsigned short u16x8 __attribute__((ext_vector_type(8)));
typedef unsigned short u16x4 __attribute__((ext_vector_type(4)));

#define NBATCH 4
#define LSEQ   2048
#define CDIM   512
#define NHEADS 8
#define DHEAD  64
// q pre-scale folds softmax exp->exp2: 0.125 * log2(e)
#define QSCALE 0.18033688011112042f

// native v_exp_f32 (computes 2^x); __exp2f fails to compile in this harness
__device__ __forceinline__ float exp2_hw(float x) {
  return __builtin_amdgcn_exp2f(x);
}

__device__ __forceinline__ u16 f2bf(float f) {
  union { float f; unsigned u; } v; v.f = f;
  return (u16)((v.u + 0x7FFFu + ((v.u >> 16) & 1u)) >> 16);  // RNE
}
__device__ __forceinline__ u16 f2bf_hw(float f) {
  union { __bf16 b; u16 u; } cv; cv.b = (__bf16)f; return cv.u;
}
__device__ __forceinline__ unsigned pack2bf(float a, float b) {
  union { bf16x2 v; unsigned u; } cv;
  cv.v[0] = (__bf16)a; cv.v[1] = (__bf16)b;
  return cv.u;
}
__device__ __forceinline__ f32x4 mfma16(bf16x8 a, bf16x8 b, f32x4 c) {
  return __builtin_amdgcn_mfma_f32_16x16x32_bf16(a, b, c, 0, 0, 0);
}
// async global->LDS, 16B/lane. lp wave-uniform; HW writes lp + lane*16.
__device__ __forceinline__ void async16(const u16* gp, const u16* lp) {
  auto* g = reinterpret_cast<const __attribute__((address_space(1))) uint32_t*>(
      reinterpret_cast<uintptr_t>(gp));
  auto* l = reinterpret_cast<__attribute__((address_space(3))) uint32_t*>(
      reinterpret_cast<uintptr_t>(lp));
  __builtin_amdgcn_global_load_lds(g, l, 16, 0, 0);
}

// ---------------------------------------------------------------------------
// Kernel 1 (merged): blocks [0,4096) transpose x -> xT bf16; [4096,5120)
// convert w_qkv/w_out -> bf16.
__global__ __launch_bounds__(256) void prep(const float* __restrict__ x,
                                            const float* __restrict__ wqkv,
                                            const float* __restrict__ wout,
                                            u16* __restrict__ xT,
                                            u16* __restrict__ wqkvb,
                                            u16* __restrict__ woutb) {
  __shared__ u16 tile[32][36];
  int b = blockIdx.x, t = threadIdx.x;
  if (b < 4096) {
    int lb = b & 63, cb = (b >> 6) & 15, n = b >> 10;
    int c = t >> 3, lq = (t & 7) * 4;
    float4 f = *(const float4*)(x + ((size_t)(n * CDIM + cb * 32 + c)) * LSEQ + lb * 32 + lq);
    u16x4 cv;
    cv[0] = f2bf(f.x); cv[1] = f2bf(f.y); cv[2] = f2bf(f.z); cv[3] = f2bf(f.w);
    *(u16x4*)&tile[c][lq] = cv;
    __syncthreads();
    int l = t >> 3, cq = (t & 7) * 4;
    u16x4 o;
    o[0] = tile[cq + 0][l]; o[1] = tile[cq + 1][l];
    o[2] = tile[cq + 2][l]; o[3] = tile[cq + 3][l];
    *(u16x4*)(xT + ((size_t)(n * LSEQ + lb * 32 + l)) * CDIM + cb * 32 + cq) = o;
  } else {
    int i = (b - 4096) * 256 + t;  // 1024 blocks * 256 = 262144 float4s
    const float4* src;
    u16* dst;
    int idx;
    if (i < 196608) { src = (const float4*)wqkv; dst = wqkvb; idx = i; }
    else            { src = (const float4*)wout; dst = woutb; idx = i - 196608; }
    float4 f = src[idx];
    u16x4 o;
    o[0] = f2bf(f.x); o[1] = f2bf(f.y); o[2] = f2bf(f.z); o[3] = f2bf(f.w);
    *(u16x4*)(dst + (size_t)idx * 4) = o;
  }
}

// ---------------------------------------------------------------------------
// Kernel 2 (m97-style): QKV GEMM, 128x128 tile, BK=64. grid: (12, 16, 4).
__global__ __launch_bounds__(256, 3) void qkv_gemm(const u16* __restrict__ wqkvb,
                                                   const u16* __restrict__ xT,
                                                   u16* __restrict__ qT,
                                                   u16* __restrict__ kT,
                                                   u16* __restrict__ vp) {
  __shared__ __align__(16) u16 lds[17408];  // main: At|Bt 2x8192; epi: 128x136
  u16* At = lds;
  u16* Bt = lds + 8192;

  int mb = blockIdx.x, lb = blockIdx.y, n = blockIdx.z;
  int o0 = mb * 128, l0 = lb * 128;
  int t = threadIdx.x, w = t >> 6, lane = t & 63, quad = lane >> 4, l15 = lane & 15;
  int wr = w >> 1, wc = w & 1;
  int lr = lane >> 3, lc = lane & 7;
  int swzS = (lc ^ lr) * 8;
  int swzR = l15 & 7;

  const u16* ag = wqkvb + (size_t)(o0 + w * 32 + lr) * CDIM + swzS;
  const u16* bg = xT + ((size_t)n * LSEQ + l0 + w * 32 + lr) * CDIM + swzS;

  f32x4 acc[4][4];
#pragma unroll
  for (int i = 0; i < 4; ++i)
#pragma unroll
    for (int j = 0; j < 4; ++j) acc[i][j] = (f32x4)0.0f;

  for (int k0 = 0; k0 < CDIM; k0 += 64) {
#pragma unroll
    for (int g = 0; g < 4; ++g) {
      async16(ag + (size_t)g * 8 * CDIM + k0, At + (w * 32 + g * 8) * 64);
      async16(bg + (size_t)g * 8 * CDIM + k0, Bt + (w * 32 + g * 8) * 64);
    }
    __syncthreads();
    bf16x8 af[4][2], bf[4][2];
#pragma unroll
    for (int rt = 0; rt < 4; ++rt)
#pragma unroll
      for (int kk = 0; kk < 2; ++kk) {
        af[rt][kk] = *(const bf16x8*)&At[(wr * 64 + rt * 16 + l15) * 64 +
                                         (((kk * 4 + quad) ^ swzR) * 8)];
        bf[rt][kk] = *(const bf16x8*)&Bt[(wc * 64 + rt * 16 + l15) * 64 +
                                         (((kk * 4 + quad) ^ swzR) * 8)];
      }
#pragma unroll
    for (int kk = 0; kk < 2; ++kk)
#pragma unroll
      for (int rt = 0; rt < 4; ++rt)
#pragma unroll
        for (int ct = 0; ct < 4; ++ct)
          acc[rt][ct] = mfma16(af[rt][kk], bf[ct][kk], acc[rt][ct]);
    __syncthreads();
  }

  int seg = mb >> 2;        // 0 q, 1 k, 2 v
  int hb = (mb & 3) * 2;    // 2 heads per block
  if (seg < 2) {
    float scale = (seg == 0) ? QSCALE : 1.0f;
#pragma unroll
    for (int rt = 0; rt < 4; ++rt)
#pragma unroll
      for (int ct = 0; ct < 4; ++ct) {
        u16x4 ov;
#pragma unroll
        for (int r = 0; r < 4; ++r) ov[r] = f2bf_hw(acc[rt][ct][r] * scale);
        *(u16x4*)&lds[(wc * 64 + ct * 16 + l15) * 136 + wr * 64 + rt * 16 + quad * 4] = ov;
      }
    __syncthreads();
    u16* dst0 = (seg == 0) ? qT : kT;
#pragma unroll
    for (int p = 0; p < 8; ++p) {
      int l = p * 16 + (t >> 4);
      int ch = t & 15;
      u16x8 val = *(const u16x8*)&lds[l * 136 + ch * 8];
      int h = hb + (ch >> 3);
      int d = (ch & 7) * 8;
      *(u16x8*)(dst0 + (((size_t)(n * NHEADS + h)) * LSEQ + l0 + l) * DHEAD + d) = val;
    }
  } else {
#pragma unroll
    for (int rt = 0; rt < 4; ++rt)
#pragma unroll
      for (int ct = 0; ct < 4; ++ct)
#pragma unroll
        for (int r = 0; r < 4; ++r)
          lds[(wr * 64 + rt * 16 + quad * 4 + r) * 136 + wc * 64 + ct * 16 + l15] =
              f2bf_hw(acc[rt][ct][r]);
    __syncthreads();
#pragma unroll
    for (int p = 0; p < 8; ++p) {
      int o = p * 16 + (t >> 4);
      int ch = t & 15;
      u16x8 val = *(const u16x8*)&lds[o * 136 + ch * 8];
      int h = hb + (o >> 6);
      int d = o & 63;
      *(u16x8*)(vp + (((size_t)(n * NHEADS + h)) * DHEAD + d) * LSEQ + l0 + ch * 8) = val;
    }
  }
}

// ---------------------------------------------------------------------------
// Kernel 3: flash attention (constant-shift softmax, no online max).
//
// R4 post-mortem: bypassing LDS (direct global->VGPR K/V) was 2.8x WORSE —
// each fragment load touches 16 cache lines, 4 waves duplicate them, and
// the kernel went VMEM-latency-bound (MfmaUtil 11%). LDS staging is the
// broadcast mechanism; DO NOT remove it. Relieve the DS pipe by reading
// LESS per wave instead.
//
// R-this: 2x2 wave decomposition. Wave (wi=w>>1, wj=w&1) owns 64 i-rows x
// 32 j-cols of each 64-j tile. kf: 2x2=4 reads, vf: 4 reads => 8
// ds_read_b128/wave-tile (was 16). MFMA/exp2/permlane counts unchanged.
// Staged LDS layout+swizzle identical to R3 (kf[jt'][kk] = old
// kf[wj*2+jt'][kk]; vf[dt] = old vf[dt][kk=wj]). R3's verified permlane
// transpose applies verbatim to the single 32-j chunk (jt'=0,1).
// O and lsum become partial over j-halves: one-time f32 reduction via LDS
// (reusing KVs, 20-float padded rows), wj=0 waves add+normalize and store
// straight to global (old Ot transpose round-trip dropped).
// T4 retained: triple-buffer K/V, 2-ahead prefetch, counted vmcnt(4) +
// raw s_barrier; PV pipelined one tile behind QK in registers.
// grid: (16, 8, 4), block 256.
__global__ __launch_bounds__(256, 2) void attn_kernel(const u16* __restrict__ qT,
                                                      const u16* __restrict__ kT,
                                                      const u16* __restrict__ vp,
                                                      u16* __restrict__ aoT) {
  __shared__ __align__(16) u16 KVs[3][8192];   // [buf][ K 64x64 | V 64x64 ]

  int ib = blockIdx.x, h = blockIdx.y, n = blockIdx.z;
  int i0 = ib * 128;
  const u16* qb = qT + ((size_t)(n * NHEADS + h)) * LSEQ * DHEAD;
  const u16* kb = kT + ((size_t)(n * NHEADS + h)) * LSEQ * DHEAD;
  const u16* vb = vp + ((size_t)(n * NHEADS + h)) * DHEAD * LSEQ;
  int t = threadIdx.x, w = t >> 6, lane = t & 63, quad = lane >> 4, l15 = lane & 15;
  int wi = w >> 1, wj = w & 1;

  // Q B-frags (resident). qf[it][kk]: Q[i = i0+wi*64+it*16+l15][kk*32+quad*8..]
  bf16x8 qf[4][2];
#pragma unroll
  for (int it = 0; it < 4; ++it)
#pragma unroll
    for (int kk = 0; kk < 2; ++kk)
      qf[it][kk] = *(const bf16x8*)(qb + (size_t)(i0 + wi * 64 + it * 16 + l15) * DHEAD +
                                    kk * 32 + quad * 8);

  f32x4 Oc[4][4];  // partial O over this wave's j-half
#pragma unroll
  for (int it = 0; it < 4; ++it)
#pragma unroll
    for (int dt = 0; dt < 4; ++dt) Oc[it][dt] = (f32x4)0.0f;
  float lsum[4] = {0.f, 0.f, 0.f, 0.f};  // per-lane partial row sums (j-half)

  int lr = lane >> 3, lc = lane & 7;
  int swz = lc ^ lr;
  const u16* kgl = kb + lr * DHEAD + swz * 8;
  const u16* vgl = vb + (size_t)lr * LSEQ + swz * 8;
  int swzK = l15 & 7;

  auto stage = [&](int j0, int b) {
#pragma unroll
    for (int s = 0; s < 2; ++s) {
      int g = s * 4 + w;
      async16(kgl + (size_t)j0 * DHEAD + g * 512, &KVs[b][g * 512]);
      async16(vgl + j0 + (size_t)g * 8 * LSEQ, &KVs[b][4096 + g * 512]);
    }
  };

  // Pipelined P/V fragments: data of tile (t-1), consumed at top of iter t.
  bf16x8 pf_c[4];  // P^T B-frags per itile (32-j chunk of this wave)
  bf16x8 vf_c[4];  // V frags (this wave's j-half)

  // Per-tile body. do_pv folds at inline (call sites pass literals).
  auto tile_body = [&](int tt, bool do_pv) {
    const u16* Kt = &KVs[tt % 3][0];
    const u16* Vt = &KVs[tt % 3][4096];

    // K A-frags: rows wj*32+16jt'+l15, d-chunk (quad+4kk)^swz. 4 reads.
    bf16x8 kf[2][2];
#pragma unroll
    for (int jt = 0; jt < 2; ++jt)
#pragma unroll
      for (int kk = 0; kk < 2; ++kk)
        kf[jt][kk] = *(const bf16x8*)&Kt[(wj * 32 + 16 * jt + l15) * 64 +
                                         (((quad + 4 * kk) ^ swzK) * 8)];

    if (do_pv) {
      // D(tt-1): PV from registers — zero LDS dependency at iter start.
#pragma unroll
      for (int it = 0; it < 4; ++it)
#pragma unroll
        for (int dt = 0; dt < 4; ++dt)
          Oc[it][dt] = mfma16(vf_c[dt], pf_c[it], Oc[it][dt]);
    }

    // QK(tt): S^T[j = wj*32+16jt'+4q+r][i = wi*64+16it+l15]
    f32x4 st[4][2];
#pragma unroll
    for (int it = 0; it < 4; ++it)
#pragma unroll
      for (int jt = 0; jt < 2; ++jt) {
        f32x4 s = (f32x4)0.0f;
        s = mfma16(kf[jt][0], qf[it][0], s);
        s = mfma16(kf[jt][1], qf[it][1], s);
        st[it][jt] = s;
      }

    // V frags for tile tt (this wave's j-half): V[16dt+l15][wj*32+quad*8..]
    // LDS chunk = (wj*4+quad)^swz. 4 reads; consumed next iter.
#pragma unroll
    for (int dt = 0; dt < 4; ++dt)
      vf_c[dt] = *(const bf16x8*)&Vt[(16 * dt + l15) * 64 +
                                     (((wj * 4 + quad) ^ swzK) * 8)];

    // C(tt): exp2 -> pack -> in-register P^T transpose via permlane swaps
    // (R3-verified: (Ah,Bh)=swap16(swap32(w[0][h],w[1][h])) -> u32 slots
    // h / 2+h of pf, j_local = 8q'+e, i preserved).
#pragma unroll
    for (int it = 0; it < 4; ++it) {
      unsigned wjh[2][2];
#pragma unroll
      for (int jt = 0; jt < 2; ++jt) {
        float p0 = exp2_hw(st[it][jt][0]);
        float p1 = exp2_hw(st[it][jt][1]);
        float p2 = exp2_hw(st[it][jt][2]);
        float p3 = exp2_hw(st[it][jt][3]);
        lsum[it] += (p0 + p1) + (p2 + p3);
        wjh[jt][0] = pack2bf(p0, p1);
        wjh[jt][1] = pack2bf(p2, p3);
      }
      unsigned a0 = wjh[0][0], b0 = wjh[1][0];
      unsigned a1 = wjh[0][1], b1 = wjh[1][1];
      asm volatile("v_permlane32_swap_b32 %0, %1" : "+v"(a0), "+v"(b0));
      asm volatile("v_permlane16_swap_b32 %0, %1" : "+v"(a0), "+v"(b0));
      asm volatile("v_permlane32_swap_b32 %0, %1" : "+v"(a1), "+v"(b1));
      asm volatile("v_permlane16_swap_b32 %0, %1" : "+v"(a1), "+v"(b1));
      union { unsigned u[4]; bf16x8 v; } cv;
      cv.u[0] = a0; cv.u[1] = a1; cv.u[2] = b0; cv.u[3] = b1;
      pf_c[it] = cv.v;
    }
  };

  stage(0, 0);
  stage(64, 1);

  // ---- Tile 0: wait own stage(0) (oldest; q loads retire with it), barrier.
  asm volatile("s_waitcnt vmcnt(4)" ::: "memory");
  __builtin_amdgcn_s_barrier();
  __builtin_amdgcn_sched_barrier(0);
  stage(128, 2);
  tile_body(0, false);

  // ---- Main loop: iter tt computes QK(tt) and PV(tt-1). One barrier/iter.
  for (int tt = 1; tt < 31; ++tt) {
    asm volatile("s_waitcnt vmcnt(4)" ::: "memory");  // stage(tt) complete
    __builtin_amdgcn_s_barrier();                     // all waves: buf[tt%3] ready,
    __builtin_amdgcn_sched_barrier(0);                // tile tt-1 reads done
    if (tt + 2 < 32) stage((tt + 2) * 64, (tt + 2) % 3);
    tile_body(tt, true);
  }

  // ---- Peeled last iter (tt=31): only stage(31) outstanding -> vmcnt(0).
  asm volatile("s_waitcnt vmcnt(0)" ::: "memory");
  __builtin_amdgcn_s_barrier();
  __builtin_amdgcn_sched_barrier(0);
  tile_body(31, true);

  // ---- Drain: PV(31) from registers ----
#pragma unroll
  for (int it = 0; it < 4; ++it)
#pragma unroll
    for (int dt = 0; dt < 4; ++dt)
      Oc[it][dt] = mfma16(vf_c[dt], pf_c[it], Oc[it][dt]);

  // ---- Epilogue: cross-quad lsum reduce, then cross-wave (wj) reduction
  // through LDS (reusing KVs; padded 20-float rows), normalize, store.
#pragma unroll
  for (int it = 0; it < 4; ++it) {
    lsum[it] += __shfl_xor(lsum[it], 16, 64);
    lsum[it] += __shfl_xor(lsum[it], 32, 64);
  }
  __syncthreads();  // all waves past tile-31 LDS reads; KVs free for reuse
  float* Os = (float*)&KVs[0][0];                 // [2wi][4it][4dt][16 i][20]
  float* Ls = (float*)((char*)&KVs[0][0] + 40960);  // [2wi][4it][16 i]
  if (wj == 1) {
#pragma unroll
    for (int it = 0; it < 4; ++it) {
#pragma unroll
      for (int dt = 0; dt < 4; ++dt)
        *(f32x4*)&Os[((((wi * 4 + it) * 4 + dt) * 16) + l15) * 20 + 4 * quad] =
            Oc[it][dt];
      if (quad == 0) Ls[(wi * 4 + it) * 16 + l15] = lsum[it];
    }
  }
  __syncthreads();
  if (wj == 0) {
#pragma unroll
    for (int it = 0; it < 4; ++it) {
      float lt = lsum[it] + Ls[(wi * 4 + it) * 16 + l15];
      float inv = 1.0f / lt;
      int row = i0 + wi * 64 + it * 16 + l15;
#pragma unroll
      for (int dt = 0; dt < 4; ++dt) {
        f32x4 part = *(const f32x4*)&Os[((((wi * 4 + it) * 4 + dt) * 16) + l15) * 20 +
                                        4 * quad];
        u16x4 ov;
#pragma unroll
        for (int r = 0; r < 4; ++r)
          ov[r] = f2bf_hw((Oc[it][dt][r] + part[r]) * inv);
        // O[i=row][d=16dt+4q+r] -> aoT[n][row][h*64+d]
        *(u16x4*)(aoT + ((size_t)n * LSEQ + row) * CDIM + h * DHEAD + 16 * dt +
                  4 * quad) = ov;
      }
    }
  }
}

// ---------------------------------------------------------------------------
// Kernel 4 (R6 two-barrier single-buffer): out GEMM + bias, 128x128 tile,
// BK=64. grid: (4, 16, 4).
__global__ __launch_bounds__(256, 3) void out_gemm(const u16* __restrict__ woutb,
                                                   const u16* __restrict__ aoT,
                                                   const float* __restrict__ bout,
                                                   float* __restrict__ out) {
  __shared__ __align__(16) u16 lds[16384];  // At|Bt 2x8192
  u16* At = lds;
  u16* Bt = lds + 8192;

  int mb = blockIdx.x, lb = blockIdx.y, n = blockIdx.z;
  int o0 = mb * 128, l0 = lb * 128;
  int t = threadIdx.x, w = t >> 6, lane = t & 63, quad = lane >> 4, l15 = lane & 15;
  int wr = w >> 1, wc = w & 1;
  int lr = lane >> 3, lc = lane & 7;
  int swzS = (lc ^ lr) * 8;
  int swzR = l15 & 7;

  const u16* ag = woutb + (size_t)(o0 + w * 32 + lr) * CDIM + swzS;
  const u16* bg = aoT + ((size_t)n * LSEQ + l0 + w * 32 + lr) * CDIM + swzS;

  f32x4 acc[4][4];
#pragma unroll
  for (int i = 0; i < 4; ++i)
#pragma unroll
    for (int j = 0; j < 4; ++j) acc[i][j] = (f32x4)0.0f;

  for (int k0 = 0; k0 < CDIM; k0 += 64) {
#pragma unroll
    for (int g = 0; g < 4; ++g) {
      async16(ag + (size_t)g * 8 * CDIM + k0, At + (w * 32 + g * 8) * 64);
      async16(bg + (size_t)g * 8 * CDIM + k0, Bt + (w * 32 + g * 8) * 64);
    }
    __syncthreads();
    bf16x8 af[4][2], bf[4][2];
#pragma unroll
    for (int rt = 0; rt < 4; ++rt)
#pragma unroll
      for (int kk = 0; kk < 2; ++kk) {
        af[rt][kk] = *(const bf16x8*)&At[(wr * 64 + rt * 16 + l15) * 64 +
                                         (((kk * 4 + quad) ^ swzR) * 8)];
        bf[rt][kk] = *(const bf16x8*)&Bt[(wc * 64 + rt * 16 + l15) * 64 +
                                         (((kk * 4 + quad) ^ swzR) * 8)];
      }
#pragma unroll
    for (int kk = 0; kk < 2; ++kk)
#pragma unroll
      for (int rt = 0; rt < 4; ++rt)
#pragma unroll
        for (int ct = 0; ct < 4; ++ct)
          acc[rt][ct] = mfma16(af[rt][kk], bf[ct][kk], acc[rt][ct]);
    __syncthreads();
  }

#pragma unroll
  for (int rt = 0; rt < 4; ++rt) {
    int orow = o0 + wr * 64 + rt * 16 + quad * 4;
#pragma unroll
    for (int r = 0; r < 4; ++r) {
      float bb = bout[orow + r];
      float* orow_p = out + ((size_t)n * CDIM + orow + r) * LSEQ + l0 + wc * 64;
#pragma unroll
      for (int ct = 0; ct < 4; ++ct)
        orow_p[ct * 16 + l15] = acc[rt][ct][r] + bb;
    }
  }
}

// ---------------------------------------------------------------------------
extern "C" void kernel_launch(void* const* d_in, const int* in_sizes, int n_in,
                              void* d_out, int out_size, void* d_ws, size_t ws_size,
                              hipStream_t stream) {
  (void)in_sizes; (void)n_in; (void)out_size; (void)ws_size;
  const float* x    = (const float*)d_in[0];  // [4,512,2048]
  const float* wqkv = (const float*)d_in[1];  // [1536,512]
  const float* wout = (const float*)d_in[2];  // [512,512]
  const float* bout = (const float*)d_in[3];  // [512]

  char* ws = (char*)d_ws;
  u16* xT    = (u16*)(ws + 0);           // x^T [n][l][c]
  u16* wqkvb = (u16*)(ws + 8388608);
  u16* woutb = (u16*)(ws + 9961472);
  u16* qT    = (u16*)(ws + 10485760);    // [n][h][l][d], pre-scaled by QSCALE
  u16* kT    = (u16*)(ws + 18874368);    // [n][h][l][d]
  u16* vp    = (u16*)(ws + 27262976);    // [n][h][d][l]
  u16* aoT   = (u16*)(ws + 35651584);    // [n][l][h*64+d]

  hipLaunchKernelGGL(prep, dim3(5120), dim3(256), 0, stream, x, wqkv, wout, xT, wqkvb, woutb);
  hipLaunchKernelGGL(qkv_gemm, dim3(12, 16, 4), dim3(256), 0, stream, wqkvb, xT, qT, kT, vp);
  hipLaunchKernelGGL(attn_kernel, dim3(16, 8, 4), dim3(256), 0, stream, qT, kT, vp, aoT);
  hipLaunchKernelGGL(out_gemm, dim3(4, 16, 4), dim3(256), 0, stream, woutb, aoT, bout,
                     (float*)d_out);
}

// Round 9
// 143.297 us; speedup vs baseline: 1.6058x; 1.0364x over previous
//
#include <hip/hip_runtime.h>
#include <hip/hip_bf16.h>
#include <stdint.h>
#include <stddef.h>

typedef unsigned short u16;
typedef __bf16 bf16x8 __attribute__((ext_vector_type(8)));
typedef __bf16 bf16x2 __attribute__((ext_vector_type(2)));
typedef float f32x4 __attribute__((ext_vector_type(4)));
typedef unsigned short u16x8 __attribute__((ext_vector_type(8)));
typedef unsigned short u16x4 __attribute__((ext_vector_type(4)));

#define NBATCH 4
#define LSEQ   2048
#define CDIM   512
#define NHEADS 8
#define DHEAD  64
// q pre-scale folds softmax exp->exp2: 0.125 * log2(e)
#define QSCALE 0.18033688011112042f

// native v_exp_f32 (computes 2^x); __exp2f fails to compile in this harness
__device__ __forceinline__ float exp2_hw(float x) {
  return __builtin_amdgcn_exp2f(x);
}

__device__ __forceinline__ u16 f2bf(float f) {
  union { float f; unsigned u; } v; v.f = f;
  return (u16)((v.u + 0x7FFFu + ((v.u >> 16) & 1u)) >> 16);  // RNE
}
__device__ __forceinline__ u16 f2bf_hw(float f) {
  union { __bf16 b; u16 u; } cv; cv.b = (__bf16)f; return cv.u;
}
__device__ __forceinline__ unsigned pack2bf(float a, float b) {
  union { bf16x2 v; unsigned u; } cv;
  cv.v[0] = (__bf16)a; cv.v[1] = (__bf16)b;
  return cv.u;
}
__device__ __forceinline__ f32x4 mfma16(bf16x8 a, bf16x8 b, f32x4 c) {
  return __builtin_amdgcn_mfma_f32_16x16x32_bf16(a, b, c, 0, 0, 0);
}
// async global->LDS, 16B/lane. lp wave-uniform; HW writes lp + lane*16.
__device__ __forceinline__ void async16(const u16* gp, const u16* lp) {
  auto* g = reinterpret_cast<const __attribute__((address_space(1))) uint32_t*>(
      reinterpret_cast<uintptr_t>(gp));
  auto* l = reinterpret_cast<__attribute__((address_space(3))) uint32_t*>(
      reinterpret_cast<uintptr_t>(lp));
  __builtin_amdgcn_global_load_lds(g, l, 16, 0, 0);
}

// ---------------------------------------------------------------------------
// Kernel 1 (merged): blocks [0,4096) transpose x -> xT bf16; [4096,5120)
// convert w_qkv/w_out -> bf16.
__global__ __launch_bounds__(256) void prep(const float* __restrict__ x,
                                            const float* __restrict__ wqkv,
                                            const float* __restrict__ wout,
                                            u16* __restrict__ xT,
                                            u16* __restrict__ wqkvb,
                                            u16* __restrict__ woutb) {
  __shared__ u16 tile[32][36];
  int b = blockIdx.x, t = threadIdx.x;
  if (b < 4096) {
    int lb = b & 63, cb = (b >> 6) & 15, n = b >> 10;
    int c = t >> 3, lq = (t & 7) * 4;
    float4 f = *(const float4*)(x + ((size_t)(n * CDIM + cb * 32 + c)) * LSEQ + lb * 32 + lq);
    u16x4 cv;
    cv[0] = f2bf(f.x); cv[1] = f2bf(f.y); cv[2] = f2bf(f.z); cv[3] = f2bf(f.w);
    *(u16x4*)&tile[c][lq] = cv;
    __syncthreads();
    int l = t >> 3, cq = (t & 7) * 4;
    u16x4 o;
    o[0] = tile[cq + 0][l]; o[1] = tile[cq + 1][l];
    o[2] = tile[cq + 2][l]; o[3] = tile[cq + 3][l];
    *(u16x4*)(xT + ((size_t)(n * LSEQ + lb * 32 + l)) * CDIM + cb * 32 + cq) = o;
  } else {
    int i = (b - 4096) * 256 + t;  // 1024 blocks * 256 = 262144 float4s
    const float4* src;
    u16* dst;
    int idx;
    if (i < 196608) { src = (const float4*)wqkv; dst = wqkvb; idx = i; }
    else            { src = (const float4*)wout; dst = woutb; idx = i - 196608; }
    float4 f = src[idx];
    u16x4 o;
    o[0] = f2bf(f.x); o[1] = f2bf(f.y); o[2] = f2bf(f.z); o[3] = f2bf(f.w);
    *(u16x4*)(dst + (size_t)idx * 4) = o;
  }
}

// ---------------------------------------------------------------------------
// Kernel 2 (m97-style): QKV GEMM, 128x128 tile, BK=64. grid: (12, 16, 4).
// NOT pipelined: triple-buffering its 32KB/step staging would cut occupancy
// 3 blocks/CU -> 1 (m132 regression mode). Left at proven 2-barrier form.
__global__ __launch_bounds__(256, 3) void qkv_gemm(const u16* __restrict__ wqkvb,
                                                   const u16* __restrict__ xT,
                                                   u16* __restrict__ qT,
                                                   u16* __restrict__ kT,
                                                   u16* __restrict__ vp) {
  __shared__ __align__(16) u16 lds[17408];  // main: At|Bt 2x8192; epi: 128x136
  u16* At = lds;
  u16* Bt = lds + 8192;

  int mb = blockIdx.x, lb = blockIdx.y, n = blockIdx.z;
  int o0 = mb * 128, l0 = lb * 128;
  int t = threadIdx.x, w = t >> 6, lane = t & 63, quad = lane >> 4, l15 = lane & 15;
  int wr = w >> 1, wc = w & 1;
  int lr = lane >> 3, lc = lane & 7;
  int swzS = (lc ^ lr) * 8;
  int swzR = l15 & 7;

  const u16* ag = wqkvb + (size_t)(o0 + w * 32 + lr) * CDIM + swzS;
  const u16* bg = xT + ((size_t)n * LSEQ + l0 + w * 32 + lr) * CDIM + swzS;

  f32x4 acc[4][4];
#pragma unroll
  for (int i = 0; i < 4; ++i)
#pragma unroll
    for (int j = 0; j < 4; ++j) acc[i][j] = (f32x4)0.0f;

  for (int k0 = 0; k0 < CDIM; k0 += 64) {
#pragma unroll
    for (int g = 0; g < 4; ++g) {
      async16(ag + (size_t)g * 8 * CDIM + k0, At + (w * 32 + g * 8) * 64);
      async16(bg + (size_t)g * 8 * CDIM + k0, Bt + (w * 32 + g * 8) * 64);
    }
    __syncthreads();
    bf16x8 af[4][2], bf[4][2];
#pragma unroll
    for (int rt = 0; rt < 4; ++rt)
#pragma unroll
      for (int kk = 0; kk < 2; ++kk) {
        af[rt][kk] = *(const bf16x8*)&At[(wr * 64 + rt * 16 + l15) * 64 +
                                         (((kk * 4 + quad) ^ swzR) * 8)];
        bf[rt][kk] = *(const bf16x8*)&Bt[(wc * 64 + rt * 16 + l15) * 64 +
                                         (((kk * 4 + quad) ^ swzR) * 8)];
      }
#pragma unroll
    for (int kk = 0; kk < 2; ++kk)
#pragma unroll
      for (int rt = 0; rt < 4; ++rt)
#pragma unroll
        for (int ct = 0; ct < 4; ++ct)
          acc[rt][ct] = mfma16(af[rt][kk], bf[ct][kk], acc[rt][ct]);
    __syncthreads();
  }

  int seg = mb >> 2;        // 0 q, 1 k, 2 v
  int hb = (mb & 3) * 2;    // 2 heads per block
  if (seg < 2) {
    float scale = (seg == 0) ? QSCALE : 1.0f;
#pragma unroll
    for (int rt = 0; rt < 4; ++rt)
#pragma unroll
      for (int ct = 0; ct < 4; ++ct) {
        u16x4 ov;
#pragma unroll
        for (int r = 0; r < 4; ++r) ov[r] = f2bf_hw(acc[rt][ct][r] * scale);
        *(u16x4*)&lds[(wc * 64 + ct * 16 + l15) * 136 + wr * 64 + rt * 16 + quad * 4] = ov;
      }
    __syncthreads();
    u16* dst0 = (seg == 0) ? qT : kT;
#pragma unroll
    for (int p = 0; p < 8; ++p) {
      int l = p * 16 + (t >> 4);
      int ch = t & 15;
      u16x8 val = *(const u16x8*)&lds[l * 136 + ch * 8];
      int h = hb + (ch >> 3);
      int d = (ch & 7) * 8;
      *(u16x8*)(dst0 + (((size_t)(n * NHEADS + h)) * LSEQ + l0 + l) * DHEAD + d) = val;
    }
  } else {
#pragma unroll
    for (int rt = 0; rt < 4; ++rt)
#pragma unroll
      for (int ct = 0; ct < 4; ++ct)
#pragma unroll
        for (int r = 0; r < 4; ++r)
          lds[(wr * 64 + rt * 16 + quad * 4 + r) * 136 + wc * 64 + ct * 16 + l15] =
              f2bf_hw(acc[rt][ct][r]);
    __syncthreads();
#pragma unroll
    for (int p = 0; p < 8; ++p) {
      int o = p * 16 + (t >> 4);
      int ch = t & 15;
      u16x8 val = *(const u16x8*)&lds[o * 136 + ch * 8];
      int h = hb + (o >> 6);
      int d = o & 63;
      *(u16x8*)(vp + (((size_t)(n * NHEADS + h)) * DHEAD + d) * LSEQ + l0 + ch * 8) = val;
    }
  }
}

// ---------------------------------------------------------------------------
// Kernel 3: flash attention — BYTE-EXACT R5 (last harness-PASSING attn,
// 45.5us). R6/R7/R8 post-mortem: the it<2 (32-row/wave) restructure failed
// correctness 3x (absmax ~3.5e-2) with no bug findable by audit (512-thread,
// lgkmcnt-drain, and 256-thread/R5-staging variants all failed identically).
// DO NOT revisit the 32-row/wave decomposition without a device-side
// debugging path. DO NOT bypass LDS staging for K/V (R4: 2.8x regression).
// 2x2 wave decomp: wave (wi,wj) owns 64 i-rows x 32 j-cols; 8 ds_read/tile.
// Triple-buffer K/V, 2-ahead prefetch, counted vmcnt(4) + raw s_barrier;
// PV pipelined one tile behind QK in registers (pf_c/vf_c); permlane P^T
// transpose; cross-wj LDS f32 reduction epilogue. grid: (16, 8, 4), 256 thr.
__global__ __launch_bounds__(256, 2) void attn_kernel(const u16* __restrict__ qT,
                                                      const u16* __restrict__ kT,
                                                      const u16* __restrict__ vp,
                                                      u16* __restrict__ aoT) {
  __shared__ __align__(16) u16 KVs[3][8192];   // [buf][ K 64x64 | V 64x64 ]

  int ib = blockIdx.x, h = blockIdx.y, n = blockIdx.z;
  int i0 = ib * 128;
  const u16* qb = qT + ((size_t)(n * NHEADS + h)) * LSEQ * DHEAD;
  const u16* kb = kT + ((size_t)(n * NHEADS + h)) * LSEQ * DHEAD;
  const u16* vb = vp + ((size_t)(n * NHEADS + h)) * DHEAD * LSEQ;
  int t = threadIdx.x, w = t >> 6, lane = t & 63, quad = lane >> 4, l15 = lane & 15;
  int wi = w >> 1, wj = w & 1;

  // Q B-frags (resident). qf[it][kk]: Q[i = i0+wi*64+it*16+l15][kk*32+quad*8..]
  bf16x8 qf[4][2];
#pragma unroll
  for (int it = 0; it < 4; ++it)
#pragma unroll
    for (int kk = 0; kk < 2; ++kk)
      qf[it][kk] = *(const bf16x8*)(qb + (size_t)(i0 + wi * 64 + it * 16 + l15) * DHEAD +
                                    kk * 32 + quad * 8);

  f32x4 Oc[4][4];  // partial O over this wave's j-half
#pragma unroll
  for (int it = 0; it < 4; ++it)
#pragma unroll
    for (int dt = 0; dt < 4; ++dt) Oc[it][dt] = (f32x4)0.0f;
  float lsum[4] = {0.f, 0.f, 0.f, 0.f};  // per-lane partial row sums (j-half)

  int lr = lane >> 3, lc = lane & 7;
  int swz = lc ^ lr;
  const u16* kgl = kb + lr * DHEAD + swz * 8;
  const u16* vgl = vb + (size_t)lr * LSEQ + swz * 8;
  int swzK = l15 & 7;

  auto stage = [&](int j0, int b) {
#pragma unroll
    for (int s = 0; s < 2; ++s) {
      int g = s * 4 + w;
      async16(kgl + (size_t)j0 * DHEAD + g * 512, &KVs[b][g * 512]);
      async16(vgl + j0 + (size_t)g * 8 * LSEQ, &KVs[b][4096 + g * 512]);
    }
  };

  // Pipelined P/V fragments: data of tile (t-1), consumed at top of iter t.
  bf16x8 pf_c[4];  // P^T B-frags per itile (32-j chunk of this wave)
  bf16x8 vf_c[4];  // V frags (this wave's j-half)

  // Per-tile body. do_pv folds at inline (call sites pass literals).
  auto tile_body = [&](int tt, bool do_pv) {
    const u16* Kt = &KVs[tt % 3][0];
    const u16* Vt = &KVs[tt % 3][4096];

    // K A-frags: rows wj*32+16jt'+l15, d-chunk (quad+4kk)^swz. 4 reads.
    bf16x8 kf[2][2];
#pragma unroll
    for (int jt = 0; jt < 2; ++jt)
#pragma unroll
      for (int kk = 0; kk < 2; ++kk)
        kf[jt][kk] = *(const bf16x8*)&Kt[(wj * 32 + 16 * jt + l15) * 64 +
                                         (((quad + 4 * kk) ^ swzK) * 8)];

    if (do_pv) {
      // D(tt-1): PV from registers — zero LDS dependency at iter start.
#pragma unroll
      for (int it = 0; it < 4; ++it)
#pragma unroll
        for (int dt = 0; dt < 4; ++dt)
          Oc[it][dt] = mfma16(vf_c[dt], pf_c[it], Oc[it][dt]);
    }

    // QK(tt): S^T[j = wj*32+16jt'+4q+r][i = wi*64+16it+l15]
    f32x4 st[4][2];
#pragma unroll
    for (int it = 0; it < 4; ++it)
#pragma unroll
      for (int jt = 0; jt < 2; ++jt) {
        f32x4 s = (f32x4)0.0f;
        s = mfma16(kf[jt][0], qf[it][0], s);
        s = mfma16(kf[jt][1], qf[it][1], s);
        st[it][jt] = s;
      }

    // V frags for tile tt (this wave's j-half): V[16dt+l15][wj*32+quad*8..]
    // LDS chunk = (wj*4+quad)^swz. 4 reads; consumed next iter.
#pragma unroll
    for (int dt = 0; dt < 4; ++dt)
      vf_c[dt] = *(const bf16x8*)&Vt[(16 * dt + l15) * 64 +
                                     (((wj * 4 + quad) ^ swzK) * 8)];

    // C(tt): exp2 -> pack -> in-register P^T transpose via permlane swaps
    // (R3-verified: (Ah,Bh)=swap16(swap32(w[0][h],w[1][h])) -> u32 slots
    // h / 2+h of pf, j_local = 8q'+e, i preserved).
#pragma unroll
    for (int it = 0; it < 4; ++it) {
      unsigned wjh[2][2];
#pragma unroll
      for (int jt = 0; jt < 2; ++jt) {
        float p0 = exp2_hw(st[it][jt][0]);
        float p1 = exp2_hw(st[it][jt][1]);
        float p2 = exp2_hw(st[it][jt][2]);
        float p3 = exp2_hw(st[it][jt][3]);
        lsum[it] += (p0 + p1) + (p2 + p3);
        wjh[jt][0] = pack2bf(p0, p1);
        wjh[jt][1] = pack2bf(p2, p3);
      }
      unsigned a0 = wjh[0][0], b0 = wjh[1][0];
      unsigned a1 = wjh[0][1], b1 = wjh[1][1];
      asm volatile("v_permlane32_swap_b32 %0, %1" : "+v"(a0), "+v"(b0));
      asm volatile("v_permlane16_swap_b32 %0, %1" : "+v"(a0), "+v"(b0));
      asm volatile("v_permlane32_swap_b32 %0, %1" : "+v"(a1), "+v"(b1));
      asm volatile("v_permlane16_swap_b32 %0, %1" : "+v"(a1), "+v"(b1));
      union { unsigned u[4]; bf16x8 v; } cv;
      cv.u[0] = a0; cv.u[1] = a1; cv.u[2] = b0; cv.u[3] = b1;
      pf_c[it] = cv.v;
    }
  };

  stage(0, 0);
  stage(64, 1);

  // ---- Tile 0: wait own stage(0) (oldest; q loads retire with it), barrier.
  asm volatile("s_waitcnt vmcnt(4)" ::: "memory");
  __builtin_amdgcn_s_barrier();
  __builtin_amdgcn_sched_barrier(0);
  stage(128, 2);
  tile_body(0, false);

  // ---- Main loop: iter tt computes QK(tt) and PV(tt-1). One barrier/iter.
  for (int tt = 1; tt < 31; ++tt) {
    asm volatile("s_waitcnt vmcnt(4)" ::: "memory");  // stage(tt) complete
    __builtin_amdgcn_s_barrier();                     // all waves: buf[tt%3] ready,
    __builtin_amdgcn_sched_barrier(0);                // tile tt-1 reads done
    if (tt + 2 < 32) stage((tt + 2) * 64, (tt + 2) % 3);
    tile_body(tt, true);
  }

  // ---- Peeled last iter (tt=31): only stage(31) outstanding -> vmcnt(0).
  asm volatile("s_waitcnt vmcnt(0)" ::: "memory");
  __builtin_amdgcn_s_barrier();
  __builtin_amdgcn_sched_barrier(0);
  tile_body(31, true);

  // ---- Drain: PV(31) from registers ----
#pragma unroll
  for (int it = 0; it < 4; ++it)
#pragma unroll
    for (int dt = 0; dt < 4; ++dt)
      Oc[it][dt] = mfma16(vf_c[dt], pf_c[it], Oc[it][dt]);

  // ---- Epilogue: cross-quad lsum reduce, then cross-wave (wj) reduction
  // through LDS (reusing KVs; padded 20-float rows), normalize, store.
#pragma unroll
  for (int it = 0; it < 4; ++it) {
    lsum[it] += __shfl_xor(lsum[it], 16, 64);
    lsum[it] += __shfl_xor(lsum[it], 32, 64);
  }
  __syncthreads();  // all waves past tile-31 LDS reads; KVs free for reuse
  float* Os = (float*)&KVs[0][0];                 // [2wi][4it][4dt][16 i][20]
  float* Ls = (float*)((char*)&KVs[0][0] + 40960);  // [2wi][4it][16 i]
  if (wj == 1) {
#pragma unroll
    for (int it = 0; it < 4; ++it) {
#pragma unroll
      for (int dt = 0; dt < 4; ++dt)
        *(f32x4*)&Os[((((wi * 4 + it) * 4 + dt) * 16) + l15) * 20 + 4 * quad] =
            Oc[it][dt];
      if (quad == 0) Ls[(wi * 4 + it) * 16 + l15] = lsum[it];
    }
  }
  __syncthreads();
  if (wj == 0) {
#pragma unroll
    for (int it = 0; it < 4; ++it) {
      float lt = lsum[it] + Ls[(wi * 4 + it) * 16 + l15];
      float inv = 1.0f / lt;
      int row = i0 + wi * 64 + it * 16 + l15;
#pragma unroll
      for (int dt = 0; dt < 4; ++dt) {
        f32x4 part = *(const f32x4*)&Os[((((wi * 4 + it) * 4 + dt) * 16) + l15) * 20 +
                                        4 * quad];
        u16x4 ov;
#pragma unroll
        for (int r = 0; r < 4; ++r)
          ov[r] = f2bf_hw((Oc[it][dt][r] + part[r]) * inv);
        // O[i=row][d=16dt+4q+r] -> aoT[n][row][h*64+d]
        *(u16x4*)(aoT + ((size_t)n * LSEQ + row) * CDIM + h * DHEAD + 16 * dt +
                  4 * quad) = ov;
      }
    }
  }
}

// ---------------------------------------------------------------------------
// Kernel 4: out GEMM + bias, 128x128 tile, BK=64. grid: (4, 16, 4) = 256
// blocks = 1 block/CU (grid-capped) — so tripling LDS is free, and the
// per-iter vmcnt(0) barrier drain had no other-wave coverage. R-this: T4
// pipeline (attn-R3/R5-proven pattern): triple-buffer staging, 2-ahead
// prefetch, counted vmcnt(8) + raw s_barrier + sched_barrier, peeled last
// iter at vmcnt(0). All ds_reads consumed within the same body (no
// cross-barrier register pipeline) — strictly safer than the attn variant.
__global__ __launch_bounds__(256) void out_gemm(const u16* __restrict__ woutb,
                                                const u16* __restrict__ aoT,
                                                const float* __restrict__ bout,
                                                float* __restrict__ out) {
  __shared__ __align__(16) u16 lds[49152];  // 3 bufs x (At 8192 | Bt 8192)

  int mb = blockIdx.x, lb = blockIdx.y, n = blockIdx.z;
  int o0 = mb * 128, l0 = lb * 128;
  int t = threadIdx.x, w = t >> 6, lane = t & 63, quad = lane >> 4, l15 = lane & 15;
  int wr = w >> 1, wc = w & 1;
  int lr = lane >> 3, lc = lane & 7;
  int swzS = (lc ^ lr) * 8;
  int swzR = l15 & 7;

  const u16* ag = woutb + (size_t)(o0 + w * 32 + lr) * CDIM + swzS;
  const u16* bg = aoT + ((size_t)n * LSEQ + l0 + w * 32 + lr) * CDIM + swzS;

  f32x4 acc[4][4];
#pragma unroll
  for (int i = 0; i < 4; ++i)
#pragma unroll
    for (int j = 0; j < 4; ++j) acc[i][j] = (f32x4)0.0f;

  // stage K-step ks (k0 = ks*64) into buffer b. 8 async16/wave.
  auto stage = [&](int ks, int b) {
    u16* At = lds + b * 16384;
    u16* Bt = At + 8192;
#pragma unroll
    for (int g = 0; g < 4; ++g) {
      async16(ag + (size_t)g * 8 * CDIM + ks * 64, At + (w * 32 + g * 8) * 64);
      async16(bg + (size_t)g * 8 * CDIM + ks * 64, Bt + (w * 32 + g * 8) * 64);
    }
  };

  // compute K-step ks from buffer ks%3; all ds_reads consumed in-body.
  auto body = [&](int ks) {
    const u16* At = lds + (ks % 3) * 16384;
    const u16* Bt = At + 8192;
    bf16x8 af[4][2], bf[4][2];
#pragma unroll
    for (int rt = 0; rt < 4; ++rt)
#pragma unroll
      for (int kk = 0; kk < 2; ++kk) {
        af[rt][kk] = *(const bf16x8*)&At[(wr * 64 + rt * 16 + l15) * 64 +
                                         (((kk * 4 + quad) ^ swzR) * 8)];
        bf[rt][kk] = *(const bf16x8*)&Bt[(wc * 64 + rt * 16 + l15) * 64 +
                                         (((kk * 4 + quad) ^ swzR) * 8)];
      }
#pragma unroll
    for (int kk = 0; kk < 2; ++kk)
#pragma unroll
      for (int rt = 0; rt < 4; ++rt)
#pragma unroll
        for (int ct = 0; ct < 4; ++ct)
          acc[rt][ct] = mfma16(af[rt][kk], bf[ct][kk], acc[rt][ct]);
  };

  stage(0, 0);
  stage(1, 1);

  // K-step 0: outstanding 16 -> vmcnt(8) retires stage(0).
  asm volatile("s_waitcnt vmcnt(8)" ::: "memory");
  __builtin_amdgcn_s_barrier();
  __builtin_amdgcn_sched_barrier(0);
  stage(2, 2);
  body(0);

  // Steps 1..6: stage(ks) complete at vmcnt(8); stage(ks+2) refills the
  // buffer whose reads finished in body(ks-1) (pre-barrier).
  for (int ks = 1; ks < 7; ++ks) {
    asm volatile("s_waitcnt vmcnt(8)" ::: "memory");
    __builtin_amdgcn_s_barrier();
    __builtin_amdgcn_sched_barrier(0);
    if (ks + 2 < 8) stage(ks + 2, (ks + 2) % 3);
    body(ks);
  }

  // Peeled step 7: only stage(7) outstanding.
  asm volatile("s_waitcnt vmcnt(0)" ::: "memory");
  __builtin_amdgcn_s_barrier();
  __builtin_amdgcn_sched_barrier(0);
  body(7);

  // Epilogue (registers + global only; no LDS reuse, no extra sync).
#pragma unroll
  for (int rt = 0; rt < 4; ++rt) {
    int orow = o0 + wr * 64 + rt * 16 + quad * 4;
#pragma unroll
    for (int r = 0; r < 4; ++r) {
      float bb = bout[orow + r];
      float* orow_p = out + ((size_t)n * CDIM + orow + r) * LSEQ + l0 + wc * 64;
#pragma unroll
      for (int ct = 0; ct < 4; ++ct)
        orow_p[ct * 16 + l15] = acc[rt][ct][r] + bb;
    }
  }
}

// ---------------------------------------------------------------------------
extern "C" void kernel_launch(void* const* d_in, const int* in_sizes, int n_in,
                              void* d_out, int out_size, void* d_ws, size_t ws_size,
                              hipStream_t stream) {
  (void)in_sizes; (void)n_in; (void)out_size; (void)ws_size;
  const float* x    = (const float*)d_in[0];  // [4,512,2048]
  const float* wqkv = (const float*)d_in[1];  // [1536,512]
  const float* wout = (const float*)d_in[2];  // [512,512]
  const float* bout = (const float*)d_in[3];  // [512]

  char* ws = (char*)d_ws;
  u16* xT    = (u16*)(ws + 0);           // x^T [n][l][c]
  u16* wqkvb = (u16*)(ws + 8388608);
  u16* woutb = (u16*)(ws + 9961472);
  u16* qT    = (u16*)(ws + 10485760);    // [n][h][l][d], pre-scaled by QSCALE
  u16* kT    = (u16*)(ws + 18874368);    // [n][h][l][d]
  u16* vp    = (u16*)(ws + 27262976);    // [n][h][d][l]
  u16* aoT   = (u16*)(ws + 35651584);    // [n][l][h*64+d]

  hipLaunchKernelGGL(prep, dim3(5120), dim3(256), 0, stream, x, wqkv, wout, xT, wqkvb, woutb);
  hipLaunchKernelGGL(qkv_gemm, dim3(12, 16, 4), dim3(256), 0, stream, wqkvb, xT, qT, kT, vp);
  hipLaunchKernelGGL(attn_kernel, dim3(16, 8, 4), dim3(256), 0, stream, qT, kT, vp, aoT);
  hipLaunchKernelGGL(out_gemm, dim3(4, 16, 4), dim3(256), 0, stream, woutb, aoT, bout,
                     (float*)d_out);
}

// Round 11
// 138.841 us; speedup vs baseline: 1.6574x; 1.0321x over previous
//
#include <hip/hip_runtime.h>
#include <hip/hip_bf16.h>
#include <stdint.h>
#include <stddef.h>

typedef unsigned short u16;
typedef __bf16 bf16x8 __attribute__((ext_vector_type(8)));
typedef __bf16 bf16x2 __attribute__((ext_vector_type(2)));
typedef float f32x4 __attribute__((ext_vector_type(4)));
typedef unsigned short u16x8 __attribute__((ext_vector_type(8)));
typedef unsigned short u16x4 __attribute__((ext_vector_type(4)));

#define NBATCH 4
#define LSEQ   2048
#define CDIM   512
#define NHEADS 8
#define DHEAD  64
// q pre-scale folds softmax exp->exp2: 0.125 * log2(e)
#define QSCALE 0.18033688011112042f

// native v_exp_f32 (computes 2^x); __exp2f fails to compile in this harness
__device__ __forceinline__ float exp2_hw(float x) {
  return __builtin_amdgcn_exp2f(x);
}

__device__ __forceinline__ u16 f2bf(float f) {
  union { float f; unsigned u; } v; v.f = f;
  return (u16)((v.u + 0x7FFFu + ((v.u >> 16) & 1u)) >> 16);  // RNE
}
__device__ __forceinline__ u16 f2bf_hw(float f) {
  union { __bf16 b; u16 u; } cv; cv.b = (__bf16)f; return cv.u;
}
__device__ __forceinline__ unsigned pack2bf(float a, float b) {
  union { bf16x2 v; unsigned u; } cv;
  cv.v[0] = (__bf16)a; cv.v[1] = (__bf16)b;
  return cv.u;
}
__device__ __forceinline__ f32x4 mfma16(bf16x8 a, bf16x8 b, f32x4 c) {
  return __builtin_amdgcn_mfma_f32_16x16x32_bf16(a, b, c, 0, 0, 0);
}
// async global->LDS, 16B/lane. lp wave-uniform; HW writes lp + lane*16.
__device__ __forceinline__ void async16(const u16* gp, const u16* lp) {
  auto* g = reinterpret_cast<const __attribute__((address_space(1))) uint32_t*>(
      reinterpret_cast<uintptr_t>(gp));
  auto* l = reinterpret_cast<__attribute__((address_space(3))) uint32_t*>(
      reinterpret_cast<uintptr_t>(lp));
  __builtin_amdgcn_global_load_lds(g, l, 16, 0, 0);
}

// ---------------------------------------------------------------------------
// Kernel 1 (merged): blocks [0,4096) transpose x -> xT bf16; [4096,5120)
// convert w_qkv/w_out -> bf16.
__global__ __launch_bounds__(256) void prep(const float* __restrict__ x,
                                            const float* __restrict__ wqkv,
                                            const float* __restrict__ wout,
                                            u16* __restrict__ xT,
                                            u16* __restrict__ wqkvb,
                                            u16* __restrict__ woutb) {
  __shared__ u16 tile[32][36];
  int b = blockIdx.x, t = threadIdx.x;
  if (b < 4096) {
    int lb = b & 63, cb = (b >> 6) & 15, n = b >> 10;
    int c = t >> 3, lq = (t & 7) * 4;
    float4 f = *(const float4*)(x + ((size_t)(n * CDIM + cb * 32 + c)) * LSEQ + lb * 32 + lq);
    u16x4 cv;
    cv[0] = f2bf(f.x); cv[1] = f2bf(f.y); cv[2] = f2bf(f.z); cv[3] = f2bf(f.w);
    *(u16x4*)&tile[c][lq] = cv;
    __syncthreads();
    int l = t >> 3, cq = (t & 7) * 4;
    u16x4 o;
    o[0] = tile[cq + 0][l]; o[1] = tile[cq + 1][l];
    o[2] = tile[cq + 2][l]; o[3] = tile[cq + 3][l];
    *(u16x4*)(xT + ((size_t)(n * LSEQ + lb * 32 + l)) * CDIM + cb * 32 + cq) = o;
  } else {
    int i = (b - 4096) * 256 + t;  // 1024 blocks * 256 = 262144 float4s
    const float4* src;
    u16* dst;
    int idx;
    if (i < 196608) { src = (const float4*)wqkv; dst = wqkvb; idx = i; }
    else            { src = (const float4*)wout; dst = woutb; idx = i - 196608; }
    float4 f = src[idx];
    u16x4 o;
    o[0] = f2bf(f.x); o[1] = f2bf(f.y); o[2] = f2bf(f.z); o[3] = f2bf(f.w);
    *(u16x4*)(dst + (size_t)idx * 4) = o;
  }
}

// ---------------------------------------------------------------------------
// Kernel 2 (R9-exact body): QKV GEMM, 128x128 tile, BK=64, 2-barrier form.
// R10 post-mortem: the BK=32 triple-buffer pipeline FAILED replay
// re-validation (first call absmax degraded 1.95e-3 -> 6.8e-3, second check
// diverged) despite a 3x-audited swizzle — 4th audit-resistant failure, all
// involving NEW LDS staging patterns. RULE: only bench-proven staging
// geometries; no new swizzles without device-side debugging. Reverted.
// Grid remap only (XCD pinning): lb on blockIdx.x so linear id%8 = lb%8 —
// blocks sharing a B-panel (12 mb's) land on one XCD; 1MB panels L2-resident.
// grid: (16, 12, 4); mb = blockIdx.y, lb = blockIdx.x.
__global__ __launch_bounds__(256, 3) void qkv_gemm(const u16* __restrict__ wqkvb,
                                                   const u16* __restrict__ xT,
                                                   u16* __restrict__ qT,
                                                   u16* __restrict__ kT,
                                                   u16* __restrict__ vp) {
  __shared__ __align__(16) u16 lds[17408];  // main: At|Bt 2x8192; epi: 128x136
  u16* At = lds;
  u16* Bt = lds + 8192;

  int mb = blockIdx.y, lb = blockIdx.x, n = blockIdx.z;
  int o0 = mb * 128, l0 = lb * 128;
  int t = threadIdx.x, w = t >> 6, lane = t & 63, quad = lane >> 4, l15 = lane & 15;
  int wr = w >> 1, wc = w & 1;
  int lr = lane >> 3, lc = lane & 7;
  int swzS = (lc ^ lr) * 8;
  int swzR = l15 & 7;

  const u16* ag = wqkvb + (size_t)(o0 + w * 32 + lr) * CDIM + swzS;
  const u16* bg = xT + ((size_t)n * LSEQ + l0 + w * 32 + lr) * CDIM + swzS;

  f32x4 acc[4][4];
#pragma unroll
  for (int i = 0; i < 4; ++i)
#pragma unroll
    for (int j = 0; j < 4; ++j) acc[i][j] = (f32x4)0.0f;

  for (int k0 = 0; k0 < CDIM; k0 += 64) {
#pragma unroll
    for (int g = 0; g < 4; ++g) {
      async16(ag + (size_t)g * 8 * CDIM + k0, At + (w * 32 + g * 8) * 64);
      async16(bg + (size_t)g * 8 * CDIM + k0, Bt + (w * 32 + g * 8) * 64);
    }
    __syncthreads();
    bf16x8 af[4][2], bf[4][2];
#pragma unroll
    for (int rt = 0; rt < 4; ++rt)
#pragma unroll
      for (int kk = 0; kk < 2; ++kk) {
        af[rt][kk] = *(const bf16x8*)&At[(wr * 64 + rt * 16 + l15) * 64 +
                                         (((kk * 4 + quad) ^ swzR) * 8)];
        bf[rt][kk] = *(const bf16x8*)&Bt[(wc * 64 + rt * 16 + l15) * 64 +
                                         (((kk * 4 + quad) ^ swzR) * 8)];
      }
#pragma unroll
    for (int kk = 0; kk < 2; ++kk)
#pragma unroll
      for (int rt = 0; rt < 4; ++rt)
#pragma unroll
        for (int ct = 0; ct < 4; ++ct)
          acc[rt][ct] = mfma16(af[rt][kk], bf[ct][kk], acc[rt][ct]);
    __syncthreads();
  }

  int seg = mb >> 2;        // 0 q, 1 k, 2 v
  int hb = (mb & 3) * 2;    // 2 heads per block
  if (seg < 2) {
    float scale = (seg == 0) ? QSCALE : 1.0f;
#pragma unroll
    for (int rt = 0; rt < 4; ++rt)
#pragma unroll
      for (int ct = 0; ct < 4; ++ct) {
        u16x4 ov;
#pragma unroll
        for (int r = 0; r < 4; ++r) ov[r] = f2bf_hw(acc[rt][ct][r] * scale);
        *(u16x4*)&lds[(wc * 64 + ct * 16 + l15) * 136 + wr * 64 + rt * 16 + quad * 4] = ov;
      }
    __syncthreads();
    u16* dst0 = (seg == 0) ? qT : kT;
#pragma unroll
    for (int p = 0; p < 8; ++p) {
      int l = p * 16 + (t >> 4);
      int ch = t & 15;
      u16x8 val = *(const u16x8*)&lds[l * 136 + ch * 8];
      int h = hb + (ch >> 3);
      int d = (ch & 7) * 8;
      *(u16x8*)(dst0 + (((size_t)(n * NHEADS + h)) * LSEQ + l0 + l) * DHEAD + d) = val;
    }
  } else {
#pragma unroll
    for (int rt = 0; rt < 4; ++rt)
#pragma unroll
      for (int ct = 0; ct < 4; ++ct)
#pragma unroll
        for (int r = 0; r < 4; ++r)
          lds[(wr * 64 + rt * 16 + quad * 4 + r) * 136 + wc * 64 + ct * 16 + l15] =
              f2bf_hw(acc[rt][ct][r]);
    __syncthreads();
#pragma unroll
    for (int p = 0; p < 8; ++p) {
      int o = p * 16 + (t >> 4);
      int ch = t & 15;
      u16x8 val = *(const u16x8*)&lds[o * 136 + ch * 8];
      int h = hb + (o >> 6);
      int d = o & 63;
      *(u16x8*)(vp + (((size_t)(n * NHEADS + h)) * DHEAD + d) * LSEQ + l0 + ch * 8) = val;
    }
  }
}

// ---------------------------------------------------------------------------
// Kernel 3: flash attention — R9 body + two safe deltas:
// (1) lgkmcnt(0) added to barrier waits (strictly stronger ordering; closes
//     the latent cross-barrier vf_c window from the R6 analysis — a wave now
//     drains its OWN ds_reads before the barrier, so post-barrier DMA cannot
//     corrupt them; cannot introduce corruption by construction).
// (2) XCD pinning: grid (h=8, ib=16, n=4) so linear id%8 = h; per-XCD K/V
//     working set = 2MB < 4MB L2 (was spread over all XCDs, ~3.9x refetch).
// R6/R7/R8: 32-row/wave restructure failed 3x — closed. R4: no LDS bypass.
// 2x2 wave decomp (64 i x 32 j per wave); triple-buffer K/V; 2-ahead
// prefetch; counted vmcnt; PV one-behind in registers; permlane P^T
// transpose; cross-wj LDS f32 reduction epilogue. grid: (8, 16, 4), 256 thr.
__global__ __launch_bounds__(256, 2) void attn_kernel(const u16* __restrict__ qT,
                                                      const u16* __restrict__ kT,
                                                      const u16* __restrict__ vp,
                                                      u16* __restrict__ aoT) {
  __shared__ __align__(16) u16 KVs[3][8192];   // [buf][ K 64x64 | V 64x64 ]

  int h = blockIdx.x, ib = blockIdx.y, n = blockIdx.z;
  int i0 = ib * 128;
  const u16* qb = qT + ((size_t)(n * NHEADS + h)) * LSEQ * DHEAD;
  const u16* kb = kT + ((size_t)(n * NHEADS + h)) * LSEQ * DHEAD;
  const u16* vb = vp + ((size_t)(n * NHEADS + h)) * DHEAD * LSEQ;
  int t = threadIdx.x, w = t >> 6, lane = t & 63, quad = lane >> 4, l15 = lane & 15;
  int wi = w >> 1, wj = w & 1;

  // Q B-frags (resident). qf[it][kk]: Q[i = i0+wi*64+it*16+l15][kk*32+quad*8..]
  bf16x8 qf[4][2];
#pragma unroll
  for (int it = 0; it < 4; ++it)
#pragma unroll
    for (int kk = 0; kk < 2; ++kk)
      qf[it][kk] = *(const bf16x8*)(qb + (size_t)(i0 + wi * 64 + it * 16 + l15) * DHEAD +
                                    kk * 32 + quad * 8);

  f32x4 Oc[4][4];  // partial O over this wave's j-half
#pragma unroll
  for (int it = 0; it < 4; ++it)
#pragma unroll
    for (int dt = 0; dt < 4; ++dt) Oc[it][dt] = (f32x4)0.0f;
  float lsum[4] = {0.f, 0.f, 0.f, 0.f};  // per-lane partial row sums (j-half)

  int lr = lane >> 3, lc = lane & 7;
  int swz = lc ^ lr;
  const u16* kgl = kb + lr * DHEAD + swz * 8;
  const u16* vgl = vb + (size_t)lr * LSEQ + swz * 8;
  int swzK = l15 & 7;

  auto stage = [&](int j0, int b) {
#pragma unroll
    for (int s = 0; s < 2; ++s) {
      int g = s * 4 + w;
      async16(kgl + (size_t)j0 * DHEAD + g * 512, &KVs[b][g * 512]);
      async16(vgl + j0 + (size_t)g * 8 * LSEQ, &KVs[b][4096 + g * 512]);
    }
  };

  // Pipelined P/V fragments: data of tile (t-1), consumed at top of iter t.
  bf16x8 pf_c[4];  // P^T B-frags per itile (32-j chunk of this wave)
  bf16x8 vf_c[4];  // V frags (this wave's j-half)

  // Per-tile body. do_pv folds at inline (call sites pass literals).
  auto tile_body = [&](int tt, bool do_pv) {
    const u16* Kt = &KVs[tt % 3][0];
    const u16* Vt = &KVs[tt % 3][4096];

    // K A-frags: rows wj*32+16jt'+l15, d-chunk (quad+4kk)^swz. 4 reads.
    bf16x8 kf[2][2];
#pragma unroll
    for (int jt = 0; jt < 2; ++jt)
#pragma unroll
      for (int kk = 0; kk < 2; ++kk)
        kf[jt][kk] = *(const bf16x8*)&Kt[(wj * 32 + 16 * jt + l15) * 64 +
                                         (((quad + 4 * kk) ^ swzK) * 8)];

    if (do_pv) {
      // D(tt-1): PV from registers — zero LDS dependency at iter start.
#pragma unroll
      for (int it = 0; it < 4; ++it)
#pragma unroll
        for (int dt = 0; dt < 4; ++dt)
          Oc[it][dt] = mfma16(vf_c[dt], pf_c[it], Oc[it][dt]);
    }

    // QK(tt): S^T[j = wj*32+16jt'+4q+r][i = wi*64+16it+l15]
    f32x4 st[4][2];
#pragma unroll
    for (int it = 0; it < 4; ++it)
#pragma unroll
      for (int jt = 0; jt < 2; ++jt) {
        f32x4 s = (f32x4)0.0f;
        s = mfma16(kf[jt][0], qf[it][0], s);
        s = mfma16(kf[jt][1], qf[it][1], s);
        st[it][jt] = s;
      }

    // V frags for tile tt (this wave's j-half): V[16dt+l15][wj*32+quad*8..]
    // LDS chunk = (wj*4+quad)^swz. 4 reads; consumed next iter.
#pragma unroll
    for (int dt = 0; dt < 4; ++dt)
      vf_c[dt] = *(const bf16x8*)&Vt[(16 * dt + l15) * 64 +
                                     (((wj * 4 + quad) ^ swzK) * 8)];

    // C(tt): exp2 -> pack -> in-register P^T transpose via permlane swaps
    // (R3-verified: (Ah,Bh)=swap16(swap32(w[0][h],w[1][h])) -> u32 slots
    // h / 2+h of pf, j_local = 8q'+e, i preserved).
#pragma unroll
    for (int it = 0; it < 4; ++it) {
      unsigned wjh[2][2];
#pragma unroll
      for (int jt = 0; jt < 2; ++jt) {
        float p0 = exp2_hw(st[it][jt][0]);
        float p1 = exp2_hw(st[it][jt][1]);
        float p2 = exp2_hw(st[it][jt][2]);
        float p3 = exp2_hw(st[it][jt][3]);
        lsum[it] += (p0 + p1) + (p2 + p3);
        wjh[jt][0] = pack2bf(p0, p1);
        wjh[jt][1] = pack2bf(p2, p3);
      }
      unsigned a0 = wjh[0][0], b0 = wjh[1][0];
      unsigned a1 = wjh[0][1], b1 = wjh[1][1];
      asm volatile("v_permlane32_swap_b32 %0, %1" : "+v"(a0), "+v"(b0));
      asm volatile("v_permlane16_swap_b32 %0, %1" : "+v"(a0), "+v"(b0));
      asm volatile("v_permlane32_swap_b32 %0, %1" : "+v"(a1), "+v"(b1));
      asm volatile("v_permlane16_swap_b32 %0, %1" : "+v"(a1), "+v"(b1));
      union { unsigned u[4]; bf16x8 v; } cv;
      cv.u[0] = a0; cv.u[1] = a1; cv.u[2] = b0; cv.u[3] = b1;
      pf_c[it] = cv.v;
    }
  };

  stage(0, 0);
  stage(64, 1);

  // ---- Tile 0: wait own stage(0) (oldest; q loads retire with it), barrier.
  asm volatile("s_waitcnt vmcnt(4) lgkmcnt(0)" ::: "memory");
  __builtin_amdgcn_s_barrier();
  __builtin_amdgcn_sched_barrier(0);
  stage(128, 2);
  tile_body(0, false);

  // ---- Main loop: iter tt computes QK(tt) and PV(tt-1). One barrier/iter.
  // lgkmcnt(0): drain own ds_reads before the barrier (latent-race close).
  for (int tt = 1; tt < 31; ++tt) {
    asm volatile("s_waitcnt vmcnt(4) lgkmcnt(0)" ::: "memory");  // stage(tt) done
    __builtin_amdgcn_s_barrier();                     // all waves: buf[tt%3] ready,
    __builtin_amdgcn_sched_barrier(0);                // tile tt-1 reads executed
    if (tt + 2 < 32) stage((tt + 2) * 64, (tt + 2) % 3);
    tile_body(tt, true);
  }

  // ---- Peeled last iter (tt=31): only stage(31) outstanding -> vmcnt(0).
  asm volatile("s_waitcnt vmcnt(0) lgkmcnt(0)" ::: "memory");
  __builtin_amdgcn_s_barrier();
  __builtin_amdgcn_sched_barrier(0);
  tile_body(31, true);

  // ---- Drain: PV(31) from registers ----
#pragma unroll
  for (int it = 0; it < 4; ++it)
#pragma unroll
    for (int dt = 0; dt < 4; ++dt)
      Oc[it][dt] = mfma16(vf_c[dt], pf_c[it], Oc[it][dt]);

  // ---- Epilogue: cross-quad lsum reduce, then cross-wave (wj) reduction
  // through LDS (reusing KVs; padded 20-float rows), normalize, store.
#pragma unroll
  for (int it = 0; it < 4; ++it) {
    lsum[it] += __shfl_xor(lsum[it], 16, 64);
    lsum[it] += __shfl_xor(lsum[it], 32, 64);
  }
  __syncthreads();  // all waves past tile-31 LDS reads; KVs free for reuse
  float* Os = (float*)&KVs[0][0];                 // [2wi][4it][4dt][16 i][20]
  float* Ls = (float*)((char*)&KVs[0][0] + 40960);  // [2wi][4it][16 i]
  if (wj == 1) {
#pragma unroll
    for (int it = 0; it < 4; ++it) {
#pragma unroll
      for (int dt = 0; dt < 4; ++dt)
        *(f32x4*)&Os[((((wi * 4 + it) * 4 + dt) * 16) + l15) * 20 + 4 * quad] =
            Oc[it][dt];
      if (quad == 0) Ls[(wi * 4 + it) * 16 + l15] = lsum[it];
    }
  }
  __syncthreads();
  if (wj == 0) {
#pragma unroll
    for (int it = 0; it < 4; ++it) {
      float lt = lsum[it] + Ls[(wi * 4 + it) * 16 + l15];
      float inv = 1.0f / lt;
      int row = i0 + wi * 64 + it * 16 + l15;
#pragma unroll
      for (int dt = 0; dt < 4; ++dt) {
        f32x4 part = *(const f32x4*)&Os[((((wi * 4 + it) * 4 + dt) * 16) + l15) * 20 +
                                        4 * quad];
        u16x4 ov;
#pragma unroll
        for (int r = 0; r < 4; ++r)
          ov[r] = f2bf_hw((Oc[it][dt][r] + part[r]) * inv);
        // O[i=row][d=16dt+4q+r] -> aoT[n][row][h*64+d]
        *(u16x4*)(aoT + ((size_t)n * LSEQ + row) * CDIM + h * DHEAD + 16 * dt +
                  4 * quad) = ov;
      }
    }
  }
}

// ---------------------------------------------------------------------------
// Kernel 4: out GEMM + bias — R9-exact body (harness-PASSING T4 pipeline:
// triple-buffer, 2-ahead prefetch, counted vmcnt(8) + raw s_barrier +
// sched_barrier, peeled last iter). Grid remap only (XCD pinning): lb on
// blockIdx.x. grid: (16, 4, 4); mb = blockIdx.y, lb = blockIdx.x.
__global__ __launch_bounds__(256) void out_gemm(const u16* __restrict__ woutb,
                                                const u16* __restrict__ aoT,
                                                const float* __restrict__ bout,
                                                float* __restrict__ out) {
  __shared__ __align__(16) u16 lds[49152];  // 3 bufs x (At 8192 | Bt 8192)

  int mb = blockIdx.y, lb = blockIdx.x, n = blockIdx.z;
  int o0 = mb * 128, l0 = lb * 128;
  int t = threadIdx.x, w = t >> 6, lane = t & 63, quad = lane >> 4, l15 = lane & 15;
  int wr = w >> 1, wc = w & 1;
  int lr = lane >> 3, lc = lane & 7;
  int swzS = (lc ^ lr) * 8;
  int swzR = l15 & 7;

  const u16* ag = woutb + (size_t)(o0 + w * 32 + lr) * CDIM + swzS;
  const u16* bg = aoT + ((size_t)n * LSEQ + l0 + w * 32 + lr) * CDIM + swzS;

  f32x4 acc[4][4];
#pragma unroll
  for (int i = 0; i < 4; ++i)
#pragma unroll
    for (int j = 0; j < 4; ++j) acc[i][j] = (f32x4)0.0f;

  // stage K-step ks (k0 = ks*64) into buffer b. 8 async16/wave.
  auto stage = [&](int ks, int b) {
    u16* At = lds + b * 16384;
    u16* Bt = At + 8192;
#pragma unroll
    for (int g = 0; g < 4; ++g) {
      async16(ag + (size_t)g * 8 * CDIM + ks * 64, At + (w * 32 + g * 8) * 64);
      async16(bg + (size_t)g * 8 * CDIM + ks * 64, Bt + (w * 32 + g * 8) * 64);
    }
  };

  // compute K-step ks from buffer ks%3; all ds_reads consumed in-body.
  auto body = [&](int ks) {
    const u16* At = lds + (ks % 3) * 16384;
    const u16* Bt = At + 8192;
    bf16x8 af[4][2], bf[4][2];
#pragma unroll
    for (int rt = 0; rt < 4; ++rt)
#pragma unroll
      for (int kk = 0; kk < 2; ++kk) {
        af[rt][kk] = *(const bf16x8*)&At[(wr * 64 + rt * 16 + l15) * 64 +
                                         (((kk * 4 + quad) ^ swzR) * 8)];
        bf[rt][kk] = *(const bf16x8*)&Bt[(wc * 64 + rt * 16 + l15) * 64 +
                                         (((kk * 4 + quad) ^ swzR) * 8)];
      }
#pragma unroll
    for (int kk = 0; kk < 2; ++kk)
#pragma unroll
      for (int rt = 0; rt < 4; ++rt)
#pragma unroll
        for (int ct = 0; ct < 4; ++ct)
          acc[rt][ct] = mfma16(af[rt][kk], bf[ct][kk], acc[rt][ct]);
  };

  stage(0, 0);
  stage(1, 1);

  // K-step 0: outstanding 16 -> vmcnt(8) retires stage(0).
  asm volatile("s_waitcnt vmcnt(8)" ::: "memory");
  __builtin_amdgcn_s_barrier();
  __builtin_amdgcn_sched_barrier(0);
  stage(2, 2);
  body(0);

  // Steps 1..6: stage(ks) complete at vmcnt(8); stage(ks+2) refills the
  // buffer whose reads finished in body(ks-1) (pre-barrier).
  for (int ks = 1; ks < 7; ++ks) {
    asm volatile("s_waitcnt vmcnt(8)" ::: "memory");
    __builtin_amdgcn_s_barrier();
    __builtin_amdgcn_sched_barrier(0);
    if (ks + 2 < 8) stage(ks + 2, (ks + 2) % 3);
    body(ks);
  }

  // Peeled step 7: only stage(7) outstanding.
  asm volatile("s_waitcnt vmcnt(0)" ::: "memory");
  __builtin_amdgcn_s_barrier();
  __builtin_amdgcn_sched_barrier(0);
  body(7);

  // Epilogue (registers + global only; no LDS reuse, no extra sync).
#pragma unroll
  for (int rt = 0; rt < 4; ++rt) {
    int orow = o0 + wr * 64 + rt * 16 + quad * 4;
#pragma unroll
    for (int r = 0; r < 4; ++r) {
      float bb = bout[orow + r];
      float* orow_p = out + ((size_t)n * CDIM + orow + r) * LSEQ + l0 + wc * 64;
#pragma unroll
      for (int ct = 0; ct < 4; ++ct)
        orow_p[ct * 16 + l15] = acc[rt][ct][r] + bb;
    }
  }
}

// ---------------------------------------------------------------------------
extern "C" void kernel_launch(void* const* d_in, const int* in_sizes, int n_in,
                              void* d_out, int out_size, void* d_ws, size_t ws_size,
                              hipStream_t stream) {
  (void)in_sizes; (void)n_in; (void)out_size; (void)ws_size;
  const float* x    = (const float*)d_in[0];  // [4,512,2048]
  const float* wqkv = (const float*)d_in[1];  // [1536,512]
  const float* wout = (const float*)d_in[2];  // [512,512]
  const float* bout = (const float*)d_in[3];  // [512]

  char* ws = (char*)d_ws;
  u16* xT    = (u16*)(ws + 0);           // x^T [n][l][c]
  u16* wqkvb = (u16*)(ws + 8388608);
  u16* woutb = (u16*)(ws + 9961472);
  u16* qT    = (u16*)(ws + 10485760);    // [n][h][l][d], pre-scaled by QSCALE
  u16* kT    = (u16*)(ws + 18874368);    // [n][h][l][d]
  u16* vp    = (u16*)(ws + 27262976);    // [n][h][d][l]
  u16* aoT   = (u16*)(ws + 35651584);    // [n][l][h*64+d]

  hipLaunchKernelGGL(prep, dim3(5120), dim3(256), 0, stream, x, wqkv, wout, xT, wqkvb, woutb);
  hipLaunchKernelGGL(qkv_gemm, dim3(16, 12, 4), dim3(256), 0, stream, wqkvb, xT, qT, kT, vp);
  hipLaunchKernelGGL(attn_kernel, dim3(8, 16, 4), dim3(256), 0, stream, qT, kT, vp, aoT);
  hipLaunchKernelGGL(out_gemm, dim3(16, 4, 4), dim3(256), 0, stream, woutb, aoT, bout,
                     (float*)d_out);
}